// Round 3
// baseline (2457.854 us; speedup 1.0000x reference)
//
#include <hip/hip_runtime.h>

#define BB 2
#define CIN 256
#define HH 64
#define WW 64
#define NPIX 4096
#define CD 128
#define CO2 256
#define KOUT 19
#define EPSV 1e-5f

// ---------------------------------------------------------------------------
// Naive conv3x3, SAME pad. Block = 16x16 px tile for ONE output channel.
__global__ __launch_bounds__(256) void conv_naive_kernel(
    const float* __restrict__ x, const float* __restrict__ w_pam,
    const float* __restrict__ w_cam, float* __restrict__ out)
{
  const int tile = blockIdx.x;
  const int ty0 = (tile >> 2) * 16;
  const int tx0 = (tile & 3) * 16;
  const int co = blockIdx.y;
  const int b = blockIdx.z;
  const int py = threadIdx.x >> 4, px = threadIdx.x & 15;
  const int y = ty0 + py, x0p = tx0 + px;

  const float* wc = (co < CD) ? (w_pam + (size_t)co * CIN * 9)
                              : (w_cam + (size_t)(co - CD) * CIN * 9);
  const float* xb = x + (size_t)b * CIN * NPIX;

  float acc = 0.f;
  for (int ci = 0; ci < CIN; ++ci) {
    const float* xc = xb + (size_t)ci * NPIX;
    const float* wk = wc + ci * 9;
    float wv[9];
    #pragma unroll
    for (int q = 0; q < 9; ++q) wv[q] = wk[q];
    #pragma unroll
    for (int ky = 0; ky < 3; ++ky) {
      const int yy = y + ky - 1;
      if ((unsigned)yy < (unsigned)HH) {
        const float* row = xc + yy * WW;
        #pragma unroll
        for (int kx = 0; kx < 3; ++kx) {
          const int xxx = x0p + kx - 1;
          if ((unsigned)xxx < (unsigned)WW)
            acc += row[xxx] * wv[ky * 3 + kx];
        }
      }
    }
  }
  out[((size_t)b * CO2 + co) * NPIX + y * WW + x0p] = acc;
}

// ---------------------------------------------------------------------------
__global__ __launch_bounds__(256) void gn_stats_kernel(
    const float* __restrict__ conv, float* __restrict__ meanb, float* __restrict__ rstdb)
{
  const int g = blockIdx.x;
  const float* base = conv + (size_t)g * (4 * NPIX);
  float s = 0.f, ss = 0.f;
  for (int i = threadIdx.x; i < 16384; i += 256) {
    const float v = base[i];
    s += v;
    ss += v * v;
  }
  #pragma unroll
  for (int off = 32; off > 0; off >>= 1) {
    s += __shfl_down(s, off);
    ss += __shfl_down(ss, off);
  }
  __shared__ float rs[4], rss[4];
  const int lane = threadIdx.x & 63, wv = threadIdx.x >> 6;
  if (lane == 0) { rs[wv] = s; rss[wv] = ss; }
  __syncthreads();
  if (threadIdx.x == 0) {
    const float S = rs[0] + rs[1] + rs[2] + rs[3];
    const float SS = rss[0] + rss[1] + rss[2] + rss[3];
    const float inv = 1.f / 16384.f;
    const float m = S * inv;
    const float var = SS * inv - m * m;
    meanb[g] = m;
    rstdb[g] = rsqrtf(var + EPSV);
  }
}

__global__ __launch_bounds__(256) void gn_apply_kernel(
    float* __restrict__ conv, const float* __restrict__ meanb, const float* __restrict__ rstdb,
    const float* __restrict__ sc_pam, const float* __restrict__ bi_pam,
    const float* __restrict__ sc_cam, const float* __restrict__ bi_cam)
{
  const int idx = blockIdx.x * 256 + threadIdx.x;
  const int call = (idx >> 12) & 255;
  const int g = idx >> 14;
  const int head = call >> 7;
  const int c = call & 127;
  const float sc = head ? sc_cam[c] : sc_pam[c];
  const float bi = head ? bi_cam[c] : bi_pam[c];
  const float v = conv[idx];
  const float r = (v - meanb[g]) * rstdb[g] * sc + bi;
  conv[idx] = fmaxf(r, 0.f);
}

// ---------------------------------------------------------------------------
__global__ __launch_bounds__(128) void cam_gram_naive_kernel(
    const float* __restrict__ conv, float* __restrict__ graw)
{
  const int bc = blockIdx.x;
  const int b = bc >> 7, c = bc & 127;
  const int d = threadIdx.x;
  const float* Am = conv + ((size_t)b * CO2 + CD) * NPIX;
  const float* rc = Am + (size_t)c * NPIX;
  const float* rd = Am + (size_t)d * NPIX;
  float acc = 0.f;
  for (int n = 0; n < NPIX; ++n) acc += rc[n] * rd[n];
  graw[(size_t)bc * CD + d] = acc;
}

__global__ __launch_bounds__(128) void cam_softmax_kernel(
    const float* __restrict__ graw, float* __restrict__ camw)
{
  const int bc = blockIdx.x;
  const int d = threadIdx.x;
  const float g = graw[(size_t)bc * CD + d];
  float m = g;
  #pragma unroll
  for (int off = 32; off > 0; off >>= 1) m = fmaxf(m, __shfl_xor(m, off));
  __shared__ float sm[2], ssum[2];
  const int lane = d & 63, wv = d >> 6;
  if (lane == 0) sm[wv] = m;
  __syncthreads();
  m = fmaxf(sm[0], sm[1]);
  const float e = __expf(g - m);
  float s = e;
  #pragma unroll
  for (int off = 32; off > 0; off >>= 1) s += __shfl_xor(s, off);
  if (lane == 0) ssum[wv] = s;
  __syncthreads();
  camw[(size_t)bc * CD + d] = e / (ssum[0] + ssum[1]);
}

__global__ __launch_bounds__(256) void cam_apply_naive_kernel(
    const float* __restrict__ conv, const float* __restrict__ camw, float* __restrict__ scam)
{
  const int n = blockIdx.x * 256 + threadIdx.x;
  const int c = blockIdx.y;
  const int b = blockIdx.z;
  const float* Am = conv + ((size_t)b * CO2 + CD) * NPIX;
  const float* Wr = camw + ((size_t)b * CD + c) * CD;
  float acc = 0.f;
  for (int d = 0; d < CD; ++d)
    acc += Wr[d] * Am[(size_t)d * NPIX + n];
  scam[((size_t)b * CD + c) * NPIX + n] = Am[(size_t)c * NPIX + n] + acc;
}

// ---------------------------------------------------------------------------
// Naive PAM: block per 2 queries; full score row in LDS.
__global__ __launch_bounds__(256) void pam_naive_kernel(
    const float* __restrict__ conv, float* __restrict__ spam)
{
  const int b = blockIdx.y;
  const int i0 = blockIdx.x * 2;
  const float* Bm = conv + (size_t)b * CO2 * NPIX;

  __shared__ float sS[2][4096];
  __shared__ float qv[2][128];
  __shared__ float redm0[4], redm1[4], reds0[4], reds1[4];

  const int tid = threadIdx.x;
  const int lane = tid & 63, w = tid >> 6;

  if (tid < 128) qv[0][tid] = Bm[(size_t)tid * NPIX + i0];
  else           qv[1][tid - 128] = Bm[(size_t)(tid - 128) * NPIX + i0 + 1];
  __syncthreads();

  for (int j = tid; j < NPIX; j += 256) {
    float s0 = 0.f, s1 = 0.f;
    for (int c = 0; c < CD; ++c) {
      const float v = Bm[(size_t)c * NPIX + j];
      s0 += qv[0][c] * v;
      s1 += qv[1][c] * v;
    }
    sS[0][j] = s0;
    sS[1][j] = s1;
  }

  float m0 = -1e30f, m1 = -1e30f;
  for (int j = tid; j < NPIX; j += 256) {
    m0 = fmaxf(m0, sS[0][j]);
    m1 = fmaxf(m1, sS[1][j]);
  }
  #pragma unroll
  for (int off = 32; off > 0; off >>= 1) {
    m0 = fmaxf(m0, __shfl_xor(m0, off));
    m1 = fmaxf(m1, __shfl_xor(m1, off));
  }
  if (lane == 0) { redm0[w] = m0; redm1[w] = m1; }
  __syncthreads();
  m0 = fmaxf(fmaxf(redm0[0], redm0[1]), fmaxf(redm0[2], redm0[3]));
  m1 = fmaxf(fmaxf(redm1[0], redm1[1]), fmaxf(redm1[2], redm1[3]));

  float s0a = 0.f, s1a = 0.f;
  for (int j = tid; j < NPIX; j += 256) {
    const float e0 = __expf(sS[0][j] - m0);
    const float e1 = __expf(sS[1][j] - m1);
    sS[0][j] = e0; sS[1][j] = e1;
    s0a += e0; s1a += e1;
  }
  #pragma unroll
  for (int off = 32; off > 0; off >>= 1) {
    s0a += __shfl_xor(s0a, off);
    s1a += __shfl_xor(s1a, off);
  }
  if (lane == 0) { reds0[w] = s0a; reds1[w] = s1a; }
  __syncthreads();
  const float l0 = reds0[0] + reds0[1] + reds0[2] + reds0[3];
  const float l1 = reds1[0] + reds1[1] + reds1[2] + reds1[3];

  for (int ci = 0; ci < 32; ++ci) {
    const int c = w * 32 + ci;
    const float* row = Bm + (size_t)c * NPIX;
    float a0 = 0.f, a1 = 0.f;
    for (int k = 0; k < 64; ++k) {
      const int j = lane + 64 * k;
      const float v = row[j];
      a0 += sS[0][j] * v;
      a1 += sS[1][j] * v;
    }
    #pragma unroll
    for (int off = 32; off > 0; off >>= 1) {
      a0 += __shfl_down(a0, off);
      a1 += __shfl_down(a1, off);
    }
    if (lane == 0) {
      spam[((size_t)b * CD + c) * NPIX + i0]     = row[i0] + a0 / l0;
      spam[((size_t)b * CD + c) * NPIX + i0 + 1] = row[i0 + 1] + a1 / l1;
    }
  }
}

// ---------------------------------------------------------------------------
__global__ __launch_bounds__(256) void pred_kernel(
    const float* __restrict__ spam, const float* __restrict__ scam,
    const float* __restrict__ wpred, const float* __restrict__ bpred,
    float* __restrict__ logit)
{
  const int b = blockIdx.y;
  const int p = blockIdx.x * 256 + threadIdx.x;
  float acc[KOUT];
  #pragma unroll
  for (int k = 0; k < KOUT; ++k) acc[k] = bpred[k];
  const float* sp = spam + (size_t)b * CD * NPIX + p;
  const float* sc = scam + (size_t)b * CD * NPIX + p;
  for (int c = 0; c < CD; ++c) {
    const float f = sp[(size_t)c * NPIX] + sc[(size_t)c * NPIX];
    #pragma unroll
    for (int k = 0; k < KOUT; ++k)
      acc[k] += f * wpred[k * CD + c];
  }
  #pragma unroll
  for (int k = 0; k < KOUT; ++k)
    logit[((size_t)b * KOUT + k) * NPIX + p] = acc[k];
}

__global__ __launch_bounds__(256) void upsample_kernel(
    const float* __restrict__ logit, float* __restrict__ out)
{
  const int idx = blockIdx.x * 256 + threadIdx.x;
  if (idx >= BB * KOUT * 256 * 256) return;
  const int ox = idx & 255;
  const int oy = (idx >> 8) & 255;
  const int plane = idx >> 16;
  const float* src = logit + (size_t)plane * NPIX;
  const float sy = (oy + 0.5f) * 0.25f - 0.5f;
  const float sx = (ox + 0.5f) * 0.25f - 0.5f;
  const float fyf = floorf(sy), fxf = floorf(sx);
  const float wy = sy - fyf, wx = sx - fxf;
  const int y0 = (int)fyf, x0 = (int)fxf;
  const int y0c = y0 < 0 ? 0 : y0;
  const int y1c = (y0 + 1 > 63) ? 63 : y0 + 1;
  const int x0c = x0 < 0 ? 0 : x0;
  const int x1c = (x0 + 1 > 63) ? 63 : x0 + 1;
  const float v00 = src[y0c * 64 + x0c], v01 = src[y0c * 64 + x1c];
  const float v10 = src[y1c * 64 + x0c], v11 = src[y1c * 64 + x1c];
  const float top = v00 + (v01 - v00) * wx;
  const float bot = v10 + (v11 - v10) * wx;
  out[idx] = top + (bot - top) * wy;
}

// ---------------------------------------------------------------------------
extern "C" void kernel_launch(void* const* d_in, const int* in_sizes, int n_in,
                              void* d_out, int out_size, void* d_ws, size_t ws_size,
                              hipStream_t stream) {
  (void)in_sizes; (void)n_in; (void)out_size; (void)ws_size;
  const float* x      = (const float*)d_in[0];
  const float* w_pam  = (const float*)d_in[1];
  const float* s_pam  = (const float*)d_in[2];
  const float* b_pam  = (const float*)d_in[3];
  const float* w_cam  = (const float*)d_in[4];
  const float* s_cam  = (const float*)d_in[5];
  const float* b_cam  = (const float*)d_in[6];
  const float* w_pred = (const float*)d_in[7];
  const float* b_pred = (const float*)d_in[8];
  float* out_f = (float*)d_out;
  float* ws0 = (float*)d_ws;

  // workspace layout (floats) — total 2,318,336 floats = 9.27 MB
  float* conv  = ws0;                         // 2,097,152
  float* graw  = ws0 + 2097152;               // 32,768
  float* camw  = ws0 + 2097152 + 32768;       // 32,768
  float* meanb = ws0 + 2097152 + 65536;       // 128
  float* rstdb = ws0 + 2097152 + 65536 + 128; // 128
  float* logit = ws0 + 2097152 + 65536 + 256; // 155,648

  // d_out doubles as scratch for spam/scam (2,097,152 <= 2,490,368 floats);
  // upsample_kernel fully rewrites d_out at the end of every call.
  float* spam = out_f;
  float* scam = out_f + 1048576;

  conv_naive_kernel<<<dim3(16, 256, 2), 256, 0, stream>>>(x, w_pam, w_cam, conv);
  gn_stats_kernel<<<128, 256, 0, stream>>>(conv, meanb, rstdb);
  gn_apply_kernel<<<8192, 256, 0, stream>>>(conv, meanb, rstdb, s_pam, b_pam, s_cam, b_cam);
  cam_gram_naive_kernel<<<256, 128, 0, stream>>>(conv, graw);
  cam_softmax_kernel<<<256, 128, 0, stream>>>(graw, camw);
  cam_apply_naive_kernel<<<dim3(16, 128, 2), 256, 0, stream>>>(conv, camw, scam);
  pam_naive_kernel<<<dim3(2048, 2), 256, 0, stream>>>(conv, spam);
  pred_kernel<<<dim3(16, 2), 256, 0, stream>>>(spam, scam, w_pred, b_pred, logit);
  upsample_kernel<<<9728, 256, 0, stream>>>(logit, out_f);
}

// Round 5
// 912.126 us; speedup vs baseline: 2.6946x; 2.6946x over previous
//
#include <hip/hip_runtime.h>

#define BB 2
#define CIN 256
#define HH 64
#define WW 64
#define NPIX 4096
#define CD 128
#define CO2 256
#define KOUT 19
#define EPSV 1e-5f

// ---------------------------------------------------------------------------
// Tiled conv3x3 (both heads fused: co 0..127 = pam, 128..255 = cam), SAME pad.
// Block: 256 thr = 16x16 spatial tile, 32 output channels; per-thread 4co x 2x4 px.
__global__ __launch_bounds__(256) void conv3x3_kernel(
    const float* __restrict__ x, const float* __restrict__ w_pam,
    const float* __restrict__ w_cam, float* __restrict__ out)
{
  const int tile = blockIdx.x;
  const int ty0 = (tile >> 2) * 16;
  const int tx0 = (tile & 3) * 16;
  const int co0 = blockIdx.y * 32;
  const int b = blockIdx.z;
  const float* wsrc = (co0 < CD) ? (w_pam + (size_t)co0 * CIN * 9)
                                 : (w_cam + (size_t)(co0 - CD) * CIN * 9);

  __shared__ float xs[18][19];
  __shared__ float wsm[32][9];   // 288 elements: staged by 256 threads + 32 seconds

  const int tid = threadIdx.x;
  const int cog = tid >> 5;
  const int pos = tid & 31;
  const int pr = pos >> 2;
  const int pc = pos & 3;

  // x halo staging (324 elements = 256 + 68)
  const int r1 = tid / 18, c1 = tid - 18 * r1;
  const int gy1 = ty0 + r1 - 1, gx1 = tx0 + c1 - 1;
  const bool ok1 = (gy1 >= 0 && gy1 < HH && gx1 >= 0 && gx1 < WW);
  const int off1 = ok1 ? (gy1 * WW + gx1) : 0;
  const int idx2 = tid + 256;
  const int r2 = idx2 / 18, c2 = idx2 - 18 * r2;
  const int gy2 = ty0 + r2 - 1, gx2 = tx0 + c2 - 1;
  const bool has2 = (idx2 < 324);
  const bool ok2 = has2 && (gy2 >= 0 && gy2 < HH && gx2 >= 0 && gx2 < WW);
  const int off2 = ok2 ? (gy2 * WW + gx2) : 0;

  // weight staging (288 elements = 256 + 32). BUGFIX: second element for tid<32.
  const int cow = tid / 9, kw = tid - 9 * cow;              // element tid (0..255)
  const float* wp = wsrc + ((size_t)cow * CIN * 9 + kw);
  const int idxw2 = tid + 256;                              // element 256..287
  const bool hasw2 = (idxw2 < 288);
  const int cow2 = idxw2 / 9, kw2 = idxw2 - 9 * cow2;
  const float* wp2 = wsrc + (hasw2 ? ((size_t)cow2 * CIN * 9 + kw2) : 0);

  float acc[4][2][4];
  #pragma unroll
  for (int i = 0; i < 4; ++i)
    #pragma unroll
    for (int r = 0; r < 2; ++r)
      #pragma unroll
      for (int c = 0; c < 4; ++c) acc[i][r][c] = 0.f;

  const float* xb = x + (size_t)b * CIN * NPIX;

  for (int ci = 0; ci < CIN; ++ci) {
    const float* xc = xb + (size_t)ci * NPIX;
    xs[r1][c1] = ok1 ? xc[off1] : 0.f;
    if (has2) xs[r2][c2] = ok2 ? xc[off2] : 0.f;
    wsm[cow][kw] = wp[ci * 9];
    if (hasw2) wsm[cow2][kw2] = wp2[ci * 9];
    __syncthreads();

    float xr[4][6];
    #pragma unroll
    for (int r = 0; r < 4; ++r)
      #pragma unroll
      for (int c = 0; c < 6; ++c)
        xr[r][c] = xs[2 * pr + r][4 * pc + c];

    #pragma unroll
    for (int i = 0; i < 4; ++i) {
      #pragma unroll
      for (int ky = 0; ky < 3; ++ky)
        #pragma unroll
        for (int kx = 0; kx < 3; ++kx) {
          const float wv = wsm[4 * cog + i][ky * 3 + kx];
          #pragma unroll
          for (int r = 0; r < 2; ++r)
            #pragma unroll
            for (int c = 0; c < 4; ++c)
              acc[i][r][c] += xr[r + ky][c + kx] * wv;
        }
    }
    __syncthreads();
  }

  #pragma unroll
  for (int i = 0; i < 4; ++i) {
    const int co = co0 + 4 * cog + i;
    float* op = out + ((size_t)b * CO2 + co) * NPIX;
    #pragma unroll
    for (int r = 0; r < 2; ++r) {
      const int y = ty0 + 2 * pr + r;
      float4 v = make_float4(acc[i][r][0], acc[i][r][1], acc[i][r][2], acc[i][r][3]);
      *reinterpret_cast<float4*>(&op[y * WW + tx0 + 4 * pc]) = v;
    }
  }
}

// ---------------------------------------------------------------------------
__global__ __launch_bounds__(256) void gn_stats_kernel(
    const float* __restrict__ conv, float* __restrict__ meanb, float* __restrict__ rstdb)
{
  const int g = blockIdx.x;
  const float* base = conv + (size_t)g * (4 * NPIX);
  float s = 0.f, ss = 0.f;
  const float4* b4 = reinterpret_cast<const float4*>(base);
  for (int i = threadIdx.x; i < 4096; i += 256) {
    float4 v = b4[i];
    s += v.x + v.y + v.z + v.w;
    ss += v.x * v.x + v.y * v.y + v.z * v.z + v.w * v.w;
  }
  #pragma unroll
  for (int off = 32; off > 0; off >>= 1) {
    s += __shfl_down(s, off);
    ss += __shfl_down(ss, off);
  }
  __shared__ float rs[4], rss[4];
  const int lane = threadIdx.x & 63, wv = threadIdx.x >> 6;
  if (lane == 0) { rs[wv] = s; rss[wv] = ss; }
  __syncthreads();
  if (threadIdx.x == 0) {
    const float S = rs[0] + rs[1] + rs[2] + rs[3];
    const float SS = rss[0] + rss[1] + rss[2] + rss[3];
    const float inv = 1.f / 16384.f;
    const float m = S * inv;
    const float var = SS * inv - m * m;
    meanb[g] = m;
    rstdb[g] = rsqrtf(var + EPSV);
  }
}

__global__ __launch_bounds__(256) void gn_apply_kernel(
    float* __restrict__ conv, const float* __restrict__ meanb, const float* __restrict__ rstdb,
    const float* __restrict__ sc_pam, const float* __restrict__ bi_pam,
    const float* __restrict__ sc_cam, const float* __restrict__ bi_cam)
{
  const int idx = blockIdx.x * 256 + threadIdx.x;
  const int call = (idx >> 12) & 255;
  const int g = idx >> 14;
  const int head = call >> 7;
  const int c = call & 127;
  const float sc = head ? sc_cam[c] : sc_pam[c];
  const float bi = head ? bi_cam[c] : bi_pam[c];
  const float v = conv[idx];
  const float r = (v - meanb[g]) * rstdb[g] * sc + bi;
  conv[idx] = fmaxf(r, 0.f);
}

// ---------------------------------------------------------------------------
__global__ __launch_bounds__(128) void cam_gram_naive_kernel(
    const float* __restrict__ conv, float* __restrict__ graw)
{
  const int bc = blockIdx.x;
  const int b = bc >> 7, c = bc & 127;
  const int d = threadIdx.x;
  const float* Am = conv + ((size_t)b * CO2 + CD) * NPIX;
  const float* rc = Am + (size_t)c * NPIX;
  const float* rd = Am + (size_t)d * NPIX;
  float acc = 0.f;
  for (int n = 0; n < NPIX; ++n) acc += rc[n] * rd[n];
  graw[(size_t)bc * CD + d] = acc;
}

__global__ __launch_bounds__(128) void cam_softmax_kernel(
    const float* __restrict__ graw, float* __restrict__ camw)
{
  const int bc = blockIdx.x;
  const int d = threadIdx.x;
  const float g = graw[(size_t)bc * CD + d];
  float m = g;
  #pragma unroll
  for (int off = 32; off > 0; off >>= 1) m = fmaxf(m, __shfl_xor(m, off));
  __shared__ float sm[2], ssum[2];
  const int lane = d & 63, wv = d >> 6;
  if (lane == 0) sm[wv] = m;
  __syncthreads();
  m = fmaxf(sm[0], sm[1]);
  const float e = __expf(g - m);
  float s = e;
  #pragma unroll
  for (int off = 32; off > 0; off >>= 1) s += __shfl_xor(s, off);
  if (lane == 0) ssum[wv] = s;
  __syncthreads();
  camw[(size_t)bc * CD + d] = e / (ssum[0] + ssum[1]);
}

__global__ __launch_bounds__(256) void cam_apply_naive_kernel(
    const float* __restrict__ conv, const float* __restrict__ camw, float* __restrict__ scam)
{
  const int n = blockIdx.x * 256 + threadIdx.x;
  const int c = blockIdx.y;
  const int b = blockIdx.z;
  const float* Am = conv + ((size_t)b * CO2 + CD) * NPIX;
  const float* Wr = camw + ((size_t)b * CD + c) * CD;
  float acc = 0.f;
  for (int d = 0; d < CD; ++d)
    acc += Wr[d] * Am[(size_t)d * NPIX + n];
  scam[((size_t)b * CD + c) * NPIX + n] = Am[(size_t)c * NPIX + n] + acc;
}

// ---------------------------------------------------------------------------
// PAM flash attention (fp32), padded linear LDS layouts.
__global__ __launch_bounds__(256) void pam_flash_kernel(
    const float* __restrict__ conv, float* __restrict__ spam)
{
  const int b = blockIdx.y;
  const int q0 = blockIdx.x * 32;
  const float* Pp = conv + (size_t)b * CO2 * NPIX;

  __shared__ __align__(16) float Qs[128][34];
  __shared__ __align__(16) float Ks[128][68];
  __shared__ __align__(16) float Ss[32][68];
  __shared__ float mrow[32], lrow[32], fac[32];
  __shared__ float pmax[8][32], psum[8][32];

  const int tid = threadIdx.x;
  const int qgS = tid >> 4, jgS = tid & 15;
  const int qgO = tid & 15, cgO = tid >> 4;
  const int qS2 = tid & 31, part = tid >> 5;

  float O[2][8];
  #pragma unroll
  for (int i = 0; i < 2; ++i)
    #pragma unroll
    for (int j = 0; j < 8; ++j) O[i][j] = 0.f;

  {
    const int q = tid & 31, cq = tid >> 5;
    #pragma unroll
    for (int k = 0; k < 16; ++k) {
      const int c = cq + 8 * k;
      Qs[c][q] = Pp[(size_t)c * NPIX + q0 + q];
    }
  }
  if (tid < 32) { mrow[tid] = -1e9f; lrow[tid] = 0.f; }
  __syncthreads();

  for (int t = 0; t < NPIX / 64; ++t) {
    const int j0 = t * 64;
    {
      const int jj = tid & 15, c0s = tid >> 4;
      #pragma unroll
      for (int k = 0; k < 8; ++k) {
        const int c = c0s + 16 * k;
        const float4 v = *reinterpret_cast<const float4*>(&Pp[(size_t)c * NPIX + j0 + 4 * jj]);
        *reinterpret_cast<float4*>(&Ks[c][4 * jj]) = v;
      }
    }
    __syncthreads();

    float s00 = 0, s01 = 0, s02 = 0, s03 = 0, s10 = 0, s11 = 0, s12 = 0, s13 = 0;
    #pragma unroll 8
    for (int c = 0; c < 128; ++c) {
      const float qa = Qs[c][2 * qgS];
      const float qb = Qs[c][2 * qgS + 1];
      const float4 kv = *reinterpret_cast<const float4*>(&Ks[c][4 * jgS]);
      s00 += qa * kv.x; s01 += qa * kv.y; s02 += qa * kv.z; s03 += qa * kv.w;
      s10 += qb * kv.x; s11 += qb * kv.y; s12 += qb * kv.z; s13 += qb * kv.w;
    }
    *reinterpret_cast<float4*>(&Ss[2 * qgS][4 * jgS]) = make_float4(s00, s01, s02, s03);
    *reinterpret_cast<float4*>(&Ss[2 * qgS + 1][4 * jgS]) = make_float4(s10, s11, s12, s13);
    __syncthreads();

    {
      float lmax = -1e9f;
      #pragma unroll
      for (int j8 = 0; j8 < 8; ++j8)
        lmax = fmaxf(lmax, Ss[qS2][part * 8 + j8]);
      pmax[part][qS2] = lmax;
    }
    __syncthreads();
    if (tid < 32) {
      float m = pmax[0][tid];
      #pragma unroll
      for (int pp = 1; pp < 8; ++pp) m = fmaxf(m, pmax[pp][tid]);
      const float mold = mrow[tid];
      const float mnew = fmaxf(mold, m);
      fac[tid] = __expf(fmaxf(mold - mnew, -80.f));
      mrow[tid] = mnew;
    }
    __syncthreads();
    {
      const float mq = mrow[qS2];
      float lsum = 0.f;
      #pragma unroll
      for (int j8 = 0; j8 < 8; ++j8) {
        const int j = part * 8 + j8;
        const float e = __expf(Ss[qS2][j] - mq);
        Ss[qS2][j] = e;
        lsum += e;
      }
      psum[part][qS2] = lsum;
    }
    __syncthreads();
    if (tid < 32) {
      float s2 = psum[0][tid];
      #pragma unroll
      for (int pp = 1; pp < 8; ++pp) s2 += psum[pp][tid];
      lrow[tid] = lrow[tid] * fac[tid] + s2;
    }
    {
      const float f0 = fac[2 * qgO], f1 = fac[2 * qgO + 1];
      #pragma unroll
      for (int cc = 0; cc < 8; ++cc) { O[0][cc] *= f0; O[1][cc] *= f1; }
      #pragma unroll 2
      for (int jq = 0; jq < 16; ++jq) {
        const float4 p0 = *reinterpret_cast<const float4*>(&Ss[2 * qgO][4 * jq]);
        const float4 p1 = *reinterpret_cast<const float4*>(&Ss[2 * qgO + 1][4 * jq]);
        #pragma unroll
        for (int cc = 0; cc < 8; ++cc) {
          const int c = 16 * cc + cgO;
          const float4 v = *reinterpret_cast<const float4*>(&Ks[c][4 * jq]);
          O[0][cc] += p0.x * v.x + p0.y * v.y + p0.z * v.z + p0.w * v.w;
          O[1][cc] += p1.x * v.x + p1.y * v.y + p1.z * v.z + p1.w * v.w;
        }
      }
    }
    __syncthreads();
  }

  const float li0 = 1.f / lrow[2 * qgO];
  const float li1 = 1.f / lrow[2 * qgO + 1];
  const int nq = q0 + 2 * qgO;
  #pragma unroll
  for (int cc = 0; cc < 8; ++cc) {
    const int c = 16 * cc + cgO;
    const float base0 = Pp[(size_t)c * NPIX + nq];
    const float base1 = Pp[(size_t)c * NPIX + nq + 1];
    spam[((size_t)b * CD + c) * NPIX + nq] = base0 + O[0][cc] * li0;
    spam[((size_t)b * CD + c) * NPIX + nq + 1] = base1 + O[1][cc] * li1;
  }
}

// ---------------------------------------------------------------------------
__global__ __launch_bounds__(256) void pred_kernel(
    const float* __restrict__ spam, const float* __restrict__ scam,
    const float* __restrict__ wpred, const float* __restrict__ bpred,
    float* __restrict__ logit)
{
  const int b = blockIdx.y;
  const int p = blockIdx.x * 256 + threadIdx.x;
  float acc[KOUT];
  #pragma unroll
  for (int k = 0; k < KOUT; ++k) acc[k] = bpred[k];
  const float* sp = spam + (size_t)b * CD * NPIX + p;
  const float* sc = scam + (size_t)b * CD * NPIX + p;
  for (int c = 0; c < CD; ++c) {
    const float f = sp[(size_t)c * NPIX] + sc[(size_t)c * NPIX];
    #pragma unroll
    for (int k = 0; k < KOUT; ++k)
      acc[k] += f * wpred[k * CD + c];
  }
  #pragma unroll
  for (int k = 0; k < KOUT; ++k)
    logit[((size_t)b * KOUT + k) * NPIX + p] = acc[k];
}

__global__ __launch_bounds__(256) void upsample_kernel(
    const float* __restrict__ logit, float* __restrict__ out)
{
  const int idx = blockIdx.x * 256 + threadIdx.x;
  if (idx >= BB * KOUT * 256 * 256) return;
  const int ox = idx & 255;
  const int oy = (idx >> 8) & 255;
  const int plane = idx >> 16;
  const float* src = logit + (size_t)plane * NPIX;
  const float sy = (oy + 0.5f) * 0.25f - 0.5f;
  const float sx = (ox + 0.5f) * 0.25f - 0.5f;
  const float fyf = floorf(sy), fxf = floorf(sx);
  const float wy = sy - fyf, wx = sx - fxf;
  const int y0 = (int)fyf, x0 = (int)fxf;
  const int y0c = y0 < 0 ? 0 : y0;
  const int y1c = (y0 + 1 > 63) ? 63 : y0 + 1;
  const int x0c = x0 < 0 ? 0 : x0;
  const int x1c = (x0 + 1 > 63) ? 63 : x0 + 1;
  const float v00 = src[y0c * 64 + x0c], v01 = src[y0c * 64 + x1c];
  const float v10 = src[y1c * 64 + x0c], v11 = src[y1c * 64 + x1c];
  const float top = v00 + (v01 - v00) * wx;
  const float bot = v10 + (v11 - v10) * wx;
  out[idx] = top + (bot - top) * wy;
}

// ---------------------------------------------------------------------------
extern "C" void kernel_launch(void* const* d_in, const int* in_sizes, int n_in,
                              void* d_out, int out_size, void* d_ws, size_t ws_size,
                              hipStream_t stream) {
  (void)in_sizes; (void)n_in; (void)out_size; (void)ws_size;
  const float* x      = (const float*)d_in[0];
  const float* w_pam  = (const float*)d_in[1];
  const float* s_pam  = (const float*)d_in[2];
  const float* b_pam  = (const float*)d_in[3];
  const float* w_cam  = (const float*)d_in[4];
  const float* s_cam  = (const float*)d_in[5];
  const float* b_cam  = (const float*)d_in[6];
  const float* w_pred = (const float*)d_in[7];
  const float* b_pred = (const float*)d_in[8];
  float* out_f = (float*)d_out;
  float* ws0 = (float*)d_ws;

  float* conv  = ws0;                         // 2,097,152
  float* graw  = ws0 + 2097152;               // 32,768
  float* camw  = ws0 + 2097152 + 32768;       // 32,768
  float* meanb = ws0 + 2097152 + 65536;       // 128
  float* rstdb = ws0 + 2097152 + 65536 + 128; // 128
  float* logit = ws0 + 2097152 + 65536 + 256; // 155,648

  float* spam = out_f;
  float* scam = out_f + 1048576;

  conv3x3_kernel<<<dim3(16, 8, 2), 256, 0, stream>>>(x, w_pam, w_cam, conv);
  gn_stats_kernel<<<128, 256, 0, stream>>>(conv, meanb, rstdb);
  gn_apply_kernel<<<8192, 256, 0, stream>>>(conv, meanb, rstdb, s_pam, b_pam, s_cam, b_cam);
  cam_gram_naive_kernel<<<256, 128, 0, stream>>>(conv, graw);
  cam_softmax_kernel<<<256, 128, 0, stream>>>(graw, camw);
  cam_apply_naive_kernel<<<dim3(16, 128, 2), 256, 0, stream>>>(conv, camw, scam);
  pam_flash_kernel<<<dim3(128, 2), 256, 0, stream>>>(conv, spam);
  pred_kernel<<<dim3(16, 2), 256, 0, stream>>>(spam, scam, w_pred, b_pred, logit);
  upsample_kernel<<<9728, 256, 0, stream>>>(logit, out_f);
}

// Round 6
// 812.364 us; speedup vs baseline: 3.0256x; 1.1228x over previous
//
#include <hip/hip_runtime.h>

#define BB 2
#define CIN 256
#define HH 64
#define WW 64
#define NPIX 4096
#define CD 128
#define CO2 256
#define KOUT 19
#define EPSV 1e-5f

typedef __attribute__((ext_vector_type(8))) short bf16x8;
typedef __attribute__((ext_vector_type(4))) float f32x4;

__device__ inline unsigned short f2bf(float f) {
  unsigned u = __float_as_uint(f);
  u += 0x7fffu + ((u >> 16) & 1u);   // RNE
  return (unsigned short)(u >> 16);
}

// ---------------------------------------------------------------------------
// Tiled conv3x3 (both heads fused), SAME pad. (round-5 passing version)
__global__ __launch_bounds__(256) void conv3x3_kernel(
    const float* __restrict__ x, const float* __restrict__ w_pam,
    const float* __restrict__ w_cam, float* __restrict__ out)
{
  const int tile = blockIdx.x;
  const int ty0 = (tile >> 2) * 16;
  const int tx0 = (tile & 3) * 16;
  const int co0 = blockIdx.y * 32;
  const int b = blockIdx.z;
  const float* wsrc = (co0 < CD) ? (w_pam + (size_t)co0 * CIN * 9)
                                 : (w_cam + (size_t)(co0 - CD) * CIN * 9);

  __shared__ float xs[18][19];
  __shared__ float wsm[32][9];

  const int tid = threadIdx.x;
  const int cog = tid >> 5;
  const int pos = tid & 31;
  const int pr = pos >> 2;
  const int pc = pos & 3;

  const int r1 = tid / 18, c1 = tid - 18 * r1;
  const int gy1 = ty0 + r1 - 1, gx1 = tx0 + c1 - 1;
  const bool ok1 = (gy1 >= 0 && gy1 < HH && gx1 >= 0 && gx1 < WW);
  const int off1 = ok1 ? (gy1 * WW + gx1) : 0;
  const int idx2 = tid + 256;
  const int r2 = idx2 / 18, c2 = idx2 - 18 * r2;
  const int gy2 = ty0 + r2 - 1, gx2 = tx0 + c2 - 1;
  const bool has2 = (idx2 < 324);
  const bool ok2 = has2 && (gy2 >= 0 && gy2 < HH && gx2 >= 0 && gx2 < WW);
  const int off2 = ok2 ? (gy2 * WW + gx2) : 0;

  const int cow = tid / 9, kw = tid - 9 * cow;
  const float* wp = wsrc + ((size_t)cow * CIN * 9 + kw);
  const int idxw2 = tid + 256;
  const bool hasw2 = (idxw2 < 288);
  const int cow2 = idxw2 / 9, kw2 = idxw2 - 9 * cow2;
  const float* wp2 = wsrc + (hasw2 ? ((size_t)cow2 * CIN * 9 + kw2) : 0);

  float acc[4][2][4];
  #pragma unroll
  for (int i = 0; i < 4; ++i)
    #pragma unroll
    for (int r = 0; r < 2; ++r)
      #pragma unroll
      for (int c = 0; c < 4; ++c) acc[i][r][c] = 0.f;

  const float* xb = x + (size_t)b * CIN * NPIX;

  for (int ci = 0; ci < CIN; ++ci) {
    const float* xc = xb + (size_t)ci * NPIX;
    xs[r1][c1] = ok1 ? xc[off1] : 0.f;
    if (has2) xs[r2][c2] = ok2 ? xc[off2] : 0.f;
    wsm[cow][kw] = wp[ci * 9];
    if (hasw2) wsm[cow2][kw2] = wp2[ci * 9];
    __syncthreads();

    float xr[4][6];
    #pragma unroll
    for (int r = 0; r < 4; ++r)
      #pragma unroll
      for (int c = 0; c < 6; ++c)
        xr[r][c] = xs[2 * pr + r][4 * pc + c];

    #pragma unroll
    for (int i = 0; i < 4; ++i) {
      #pragma unroll
      for (int ky = 0; ky < 3; ++ky)
        #pragma unroll
        for (int kx = 0; kx < 3; ++kx) {
          const float wv = wsm[4 * cog + i][ky * 3 + kx];
          #pragma unroll
          for (int r = 0; r < 2; ++r)
            #pragma unroll
            for (int c = 0; c < 4; ++c)
              acc[i][r][c] += xr[r + ky][c + kx] * wv;
        }
    }
    __syncthreads();
  }

  #pragma unroll
  for (int i = 0; i < 4; ++i) {
    const int co = co0 + 4 * cog + i;
    float* op = out + ((size_t)b * CO2 + co) * NPIX;
    #pragma unroll
    for (int r = 0; r < 2; ++r) {
      const int y = ty0 + 2 * pr + r;
      float4 v = make_float4(acc[i][r][0], acc[i][r][1], acc[i][r][2], acc[i][r][3]);
      *reinterpret_cast<float4*>(&op[y * WW + tx0 + 4 * pc]) = v;
    }
  }
}

// ---------------------------------------------------------------------------
__global__ __launch_bounds__(256) void gn_stats_kernel(
    const float* __restrict__ conv, float* __restrict__ meanb, float* __restrict__ rstdb)
{
  const int g = blockIdx.x;
  const float* base = conv + (size_t)g * (4 * NPIX);
  float s = 0.f, ss = 0.f;
  const float4* b4 = reinterpret_cast<const float4*>(base);
  for (int i = threadIdx.x; i < 4096; i += 256) {
    float4 v = b4[i];
    s += v.x + v.y + v.z + v.w;
    ss += v.x * v.x + v.y * v.y + v.z * v.z + v.w * v.w;
  }
  #pragma unroll
  for (int off = 32; off > 0; off >>= 1) {
    s += __shfl_down(s, off);
    ss += __shfl_down(ss, off);
  }
  __shared__ float rs[4], rss[4];
  const int lane = threadIdx.x & 63, wv = threadIdx.x >> 6;
  if (lane == 0) { rs[wv] = s; rss[wv] = ss; }
  __syncthreads();
  if (threadIdx.x == 0) {
    const float S = rs[0] + rs[1] + rs[2] + rs[3];
    const float SS = rss[0] + rss[1] + rss[2] + rss[3];
    const float inv = 1.f / 16384.f;
    const float m = S * inv;
    const float var = SS * inv - m * m;
    meanb[g] = m;
    rstdb[g] = rsqrtf(var + EPSV);
  }
}

__global__ __launch_bounds__(256) void gn_apply_kernel(
    float* __restrict__ conv, const float* __restrict__ meanb, const float* __restrict__ rstdb,
    const float* __restrict__ sc_pam, const float* __restrict__ bi_pam,
    const float* __restrict__ sc_cam, const float* __restrict__ bi_cam)
{
  const int idx = blockIdx.x * 256 + threadIdx.x;
  const int call = (idx >> 12) & 255;
  const int g = idx >> 14;
  const int head = call >> 7;
  const int c = call & 127;
  const float sc = head ? sc_cam[c] : sc_pam[c];
  const float bi = head ? bi_cam[c] : bi_pam[c];
  const float v = conv[idx];
  const float r = (v - meanb[g]) * rstdb[g] * sc + bi;
  conv[idx] = fmaxf(r, 0.f);
}

// ---------------------------------------------------------------------------
// bf16 copies of the PAM half: Pb[c][px] and Pt[px][c].
__global__ __launch_bounds__(256) void to_bf16_kernel(
    const float* __restrict__ conv, unsigned short* __restrict__ Pb,
    unsigned short* __restrict__ Pt)
{
  const int px0 = blockIdx.x * 64;
  const int c0  = blockIdx.y * 32;
  const int b   = blockIdx.z;
  __shared__ unsigned short Tl[32][76];
  const int t = threadIdx.x;
  {
    const int cl = t >> 3, pg = t & 7;
    const float* src = conv + ((size_t)b * CO2 + c0 + cl) * NPIX + px0 + pg * 8;
    const float4 v0 = *reinterpret_cast<const float4*>(src);
    const float4 v1 = *reinterpret_cast<const float4*>(src + 4);
    unsigned short h0 = f2bf(v0.x), h1 = f2bf(v0.y), h2 = f2bf(v0.z), h3 = f2bf(v0.w);
    unsigned short h4 = f2bf(v1.x), h5 = f2bf(v1.y), h6 = f2bf(v1.z), h7 = f2bf(v1.w);
    uint4 packed;
    packed.x = (unsigned)h0 | ((unsigned)h1 << 16);
    packed.y = (unsigned)h2 | ((unsigned)h3 << 16);
    packed.z = (unsigned)h4 | ((unsigned)h5 << 16);
    packed.w = (unsigned)h6 | ((unsigned)h7 << 16);
    unsigned short* dst = Pb + ((size_t)b * CD + c0 + cl) * NPIX + px0 + pg * 8;
    *reinterpret_cast<uint4*>(dst) = packed;
    Tl[cl][pg * 8 + 0] = h0; Tl[cl][pg * 8 + 1] = h1;
    Tl[cl][pg * 8 + 2] = h2; Tl[cl][pg * 8 + 3] = h3;
    Tl[cl][pg * 8 + 4] = h4; Tl[cl][pg * 8 + 5] = h5;
    Tl[cl][pg * 8 + 6] = h6; Tl[cl][pg * 8 + 7] = h7;
  }
  __syncthreads();
  {
    const int pl = t >> 2, cg = t & 3;
    unsigned short h[8];
    #pragma unroll
    for (int i = 0; i < 8; ++i) h[i] = Tl[cg * 8 + i][pl];
    uint4 packed;
    packed.x = (unsigned)h[0] | ((unsigned)h[1] << 16);
    packed.y = (unsigned)h[2] | ((unsigned)h[3] << 16);
    packed.z = (unsigned)h[4] | ((unsigned)h[5] << 16);
    packed.w = (unsigned)h[6] | ((unsigned)h[7] << 16);
    unsigned short* dst = Pt + ((size_t)b * NPIX + px0 + pl) * CD + c0 + cg * 8;
    *reinterpret_cast<uint4*>(dst) = packed;
  }
}

// ---------------------------------------------------------------------------
// PAM flash attention via bf16 MFMA. One wave per block, TQ=16 queries.
// QK^T: S[q][j] = sum_c Pt[q][c]*Pt[j][c]; PV as O^T[c][q] = sum_j Pb[c][j]*Pt~[j][q].
__global__ __launch_bounds__(64) void pam_mfma_kernel(
    const float* __restrict__ conv, const unsigned short* __restrict__ Pb,
    const unsigned short* __restrict__ Pt, float* __restrict__ spam)
{
  const int b = blockIdx.y;
  const int q0 = blockIdx.x * 16;
  const int lane = threadIdx.x;
  const int m = lane & 15, g = lane >> 4;

  __shared__ __align__(16) unsigned short Sl[16 * 88];  // P~ tile [16 q][64 j], stride 88

  const unsigned short* PtB = Pt + (size_t)b * NPIX * CD;
  const unsigned short* PbB = Pb + (size_t)b * CD * NPIX;

  // Q fragments (loop-invariant): A[m=q][k=c]
  bf16x8 qf[4];
  #pragma unroll
  for (int kk = 0; kk < 4; ++kk)
    qf[kk] = *reinterpret_cast<const bf16x8*>(&PtB[(q0 + m) * CD + kk * 32 + g * 8]);

  f32x4 oacc[8];
  #pragma unroll
  for (int ct = 0; ct < 8; ++ct)
    #pragma unroll
    for (int r = 0; r < 4; ++r) oacc[ct][r] = 0.f;

  float mrow[4] = {-1e30f, -1e30f, -1e30f, -1e30f};
  float lrow[4] = {0.f, 0.f, 0.f, 0.f};

  for (int t = 0; t < NPIX / 64; ++t) {
    const int j0 = t * 64;
    // ---- QK^T: S tile [16 q][64 j] as 4 accumulators
    f32x4 sacc[4];
    #pragma unroll
    for (int jt = 0; jt < 4; ++jt)
      #pragma unroll
      for (int r = 0; r < 4; ++r) sacc[jt][r] = 0.f;
    #pragma unroll
    for (int jt = 0; jt < 4; ++jt) {
      #pragma unroll
      for (int kk = 0; kk < 4; ++kk) {
        const bf16x8 kf = *reinterpret_cast<const bf16x8*>(
            &PtB[(j0 + jt * 16 + m) * CD + kk * 32 + g * 8]);
        sacc[jt] = __builtin_amdgcn_mfma_f32_16x16x32_bf16(qf[kk], kf, sacc[jt], 0, 0, 0);
      }
    }
    // ---- online softmax. lane holds S[q=g*4+r][j=j0+jt*16+m]
    float fac[4];
    #pragma unroll
    for (int r = 0; r < 4; ++r) {
      float v = fmaxf(fmaxf(sacc[0][r], sacc[1][r]), fmaxf(sacc[2][r], sacc[3][r]));
      v = fmaxf(v, __shfl_xor(v, 1));
      v = fmaxf(v, __shfl_xor(v, 2));
      v = fmaxf(v, __shfl_xor(v, 4));
      v = fmaxf(v, __shfl_xor(v, 8));
      const float mn = fmaxf(mrow[r], v);
      fac[r] = __expf(fmaxf(mrow[r] - mn, -80.f));
      mrow[r] = mn;
    }
    #pragma unroll
    for (int r = 0; r < 4; ++r) {
      float ls = 0.f;
      #pragma unroll
      for (int jt = 0; jt < 4; ++jt) {
        const float e = __expf(sacc[jt][r] - mrow[r]);
        ls += e;
        Sl[(g * 4 + r) * 88 + jt * 16 + m] = f2bf(e);
      }
      ls += __shfl_xor(ls, 1);
      ls += __shfl_xor(ls, 2);
      ls += __shfl_xor(ls, 4);
      ls += __shfl_xor(ls, 8);
      lrow[r] = lrow[r] * fac[r] + ls;
    }
    // fac for q = m (O^T lane layout) via select + shfl
    const int sel = m & 3;
    float fsel = (sel == 0) ? fac[0] : (sel == 1) ? fac[1] : (sel == 2) ? fac[2] : fac[3];
    const float facq = __shfl(fsel, ((m >> 2) << 4) | sel);
    #pragma unroll
    for (int ct = 0; ct < 8; ++ct)
      #pragma unroll
      for (int r = 0; r < 4; ++r) oacc[ct][r] *= facq;
    // ---- PV: O^T[c][q] += V[c][j] * P~^T[j][q]
    bf16x8 pf[2];
    #pragma unroll
    for (int kt = 0; kt < 2; ++kt)
      pf[kt] = *reinterpret_cast<const bf16x8*>(&Sl[m * 88 + kt * 32 + g * 8]);
    #pragma unroll
    for (int ct = 0; ct < 8; ++ct) {
      #pragma unroll
      for (int kt = 0; kt < 2; ++kt) {
        const bf16x8 vf = *reinterpret_cast<const bf16x8*>(
            &PbB[(ct * 16 + m) * (size_t)NPIX + j0 + kt * 32 + g * 8]);
        oacc[ct] = __builtin_amdgcn_mfma_f32_16x16x32_bf16(vf, pf[kt], oacc[ct], 0, 0, 0);
      }
    }
  }

  // l for q = m via select + shfl
  const int sel = m & 3;
  float lsel = (sel == 0) ? lrow[0] : (sel == 1) ? lrow[1] : (sel == 2) ? lrow[2] : lrow[3];
  const float lq = __shfl(lsel, ((m >> 2) << 4) | sel);
  const float inv = 1.f / lq;
  #pragma unroll
  for (int ct = 0; ct < 8; ++ct) {
    #pragma unroll
    for (int r = 0; r < 4; ++r) {
      const int c = ct * 16 + g * 4 + r;
      const size_t o = ((size_t)b * CD + c) * NPIX + q0 + m;
      spam[o] = conv[((size_t)b * CO2 + c) * NPIX + q0 + m] + oacc[ct][r] * inv;
    }
  }
}

// ---------------------------------------------------------------------------
__global__ __launch_bounds__(128) void cam_gram_naive_kernel(
    const float* __restrict__ conv, float* __restrict__ graw)
{
  const int bc = blockIdx.x;
  const int b = bc >> 7, c = bc & 127;
  const int d = threadIdx.x;
  const float* Am = conv + ((size_t)b * CO2 + CD) * NPIX;
  const float* rc = Am + (size_t)c * NPIX;
  const float* rd = Am + (size_t)d * NPIX;
  float acc = 0.f;
  for (int n = 0; n < NPIX; ++n) acc += rc[n] * rd[n];
  graw[(size_t)bc * CD + d] = acc;
}

__global__ __launch_bounds__(128) void cam_softmax_kernel(
    const float* __restrict__ graw, float* __restrict__ camw)
{
  const int bc = blockIdx.x;
  const int d = threadIdx.x;
  const float g = graw[(size_t)bc * CD + d];
  float m = g;
  #pragma unroll
  for (int off = 32; off > 0; off >>= 1) m = fmaxf(m, __shfl_xor(m, off));
  __shared__ float sm[2], ssum[2];
  const int lane = d & 63, wv = d >> 6;
  if (lane == 0) sm[wv] = m;
  __syncthreads();
  m = fmaxf(sm[0], sm[1]);
  const float e = __expf(g - m);
  float s = e;
  #pragma unroll
  for (int off = 32; off > 0; off >>= 1) s += __shfl_xor(s, off);
  if (lane == 0) ssum[wv] = s;
  __syncthreads();
  camw[(size_t)bc * CD + d] = e / (ssum[0] + ssum[1]);
}

__global__ __launch_bounds__(256) void cam_apply_naive_kernel(
    const float* __restrict__ conv, const float* __restrict__ camw, float* __restrict__ scam)
{
  const int n = blockIdx.x * 256 + threadIdx.x;
  const int c = blockIdx.y;
  const int b = blockIdx.z;
  const float* Am = conv + ((size_t)b * CO2 + CD) * NPIX;
  const float* Wr = camw + ((size_t)b * CD + c) * CD;
  float acc = 0.f;
  for (int d = 0; d < CD; ++d)
    acc += Wr[d] * Am[(size_t)d * NPIX + n];
  scam[((size_t)b * CD + c) * NPIX + n] = Am[(size_t)c * NPIX + n] + acc;
}

// ---------------------------------------------------------------------------
__global__ __launch_bounds__(256) void pred_kernel(
    const float* __restrict__ spam, const float* __restrict__ scam,
    const float* __restrict__ wpred, const float* __restrict__ bpred,
    float* __restrict__ logit)
{
  const int b = blockIdx.y;
  const int p = blockIdx.x * 256 + threadIdx.x;
  float acc[KOUT];
  #pragma unroll
  for (int k = 0; k < KOUT; ++k) acc[k] = bpred[k];
  const float* sp = spam + (size_t)b * CD * NPIX + p;
  const float* sc = scam + (size_t)b * CD * NPIX + p;
  for (int c = 0; c < CD; ++c) {
    const float f = sp[(size_t)c * NPIX] + sc[(size_t)c * NPIX];
    #pragma unroll
    for (int k = 0; k < KOUT; ++k)
      acc[k] += f * wpred[k * CD + c];
  }
  #pragma unroll
  for (int k = 0; k < KOUT; ++k)
    logit[((size_t)b * KOUT + k) * NPIX + p] = acc[k];
}

__global__ __launch_bounds__(256) void upsample_kernel(
    const float* __restrict__ logit, float* __restrict__ out)
{
  const int idx = blockIdx.x * 256 + threadIdx.x;
  if (idx >= BB * KOUT * 256 * 256) return;
  const int ox = idx & 255;
  const int oy = (idx >> 8) & 255;
  const int plane = idx >> 16;
  const float* src = logit + (size_t)plane * NPIX;
  const float sy = (oy + 0.5f) * 0.25f - 0.5f;
  const float sx = (ox + 0.5f) * 0.25f - 0.5f;
  const float fyf = floorf(sy), fxf = floorf(sx);
  const float wy = sy - fyf, wx = sx - fxf;
  const int y0 = (int)fyf, x0 = (int)fxf;
  const int y0c = y0 < 0 ? 0 : y0;
  const int y1c = (y0 + 1 > 63) ? 63 : y0 + 1;
  const int x0c = x0 < 0 ? 0 : x0;
  const int x1c = (x0 + 1 > 63) ? 63 : x0 + 1;
  const float v00 = src[y0c * 64 + x0c], v01 = src[y0c * 64 + x1c];
  const float v10 = src[y1c * 64 + x0c], v11 = src[y1c * 64 + x1c];
  const float top = v00 + (v01 - v00) * wx;
  const float bot = v10 + (v11 - v10) * wx;
  out[idx] = top + (bot - top) * wy;
}

// ---------------------------------------------------------------------------
extern "C" void kernel_launch(void* const* d_in, const int* in_sizes, int n_in,
                              void* d_out, int out_size, void* d_ws, size_t ws_size,
                              hipStream_t stream) {
  (void)in_sizes; (void)n_in; (void)out_size; (void)ws_size;
  const float* x      = (const float*)d_in[0];
  const float* w_pam  = (const float*)d_in[1];
  const float* s_pam  = (const float*)d_in[2];
  const float* b_pam  = (const float*)d_in[3];
  const float* w_cam  = (const float*)d_in[4];
  const float* s_cam  = (const float*)d_in[5];
  const float* b_cam  = (const float*)d_in[6];
  const float* w_pred = (const float*)d_in[7];
  const float* b_pred = (const float*)d_in[8];
  float* out_f = (float*)d_out;
  float* ws0 = (float*)d_ws;

  // workspace layout (floats) — total 3,366,912 floats = 13.47 MB
  float* conv  = ws0;                         // 2,097,152
  float* graw  = ws0 + 2097152;               // 32,768
  float* camw  = ws0 + 2097152 + 32768;       // 32,768
  float* meanb = ws0 + 2097152 + 65536;       // 128
  float* rstdb = ws0 + 2097152 + 65536 + 128; // 128
  float* logit = ws0 + 2097152 + 65536 + 256; // 155,648
  unsigned short* Pb = (unsigned short*)(ws0 + 2318336);  // 1,048,576 bf16 = 524,288 fl
  unsigned short* Pt = (unsigned short*)(ws0 + 2842624);  // 1,048,576 bf16

  // d_out doubles as scratch for spam/scam; upsample fully rewrites d_out.
  float* spam = out_f;
  float* scam = out_f + 1048576;

  conv3x3_kernel<<<dim3(16, 8, 2), 256, 0, stream>>>(x, w_pam, w_cam, conv);
  gn_stats_kernel<<<128, 256, 0, stream>>>(conv, meanb, rstdb);
  gn_apply_kernel<<<8192, 256, 0, stream>>>(conv, meanb, rstdb, s_pam, b_pam, s_cam, b_cam);
  to_bf16_kernel<<<dim3(64, 4, 2), 256, 0, stream>>>(conv, Pb, Pt);
  cam_gram_naive_kernel<<<256, 128, 0, stream>>>(conv, graw);
  cam_softmax_kernel<<<256, 128, 0, stream>>>(graw, camw);
  cam_apply_naive_kernel<<<dim3(16, 128, 2), 256, 0, stream>>>(conv, camw, scam);
  pam_mfma_kernel<<<dim3(256, 2), 64, 0, stream>>>(conv, Pb, Pt, spam);
  pred_kernel<<<dim3(16, 2), 256, 0, stream>>>(spam, scam, w_pred, b_pred, logit);
  upsample_kernel<<<9728, 256, 0, stream>>>(logit, out_f);
}

// Round 8
// 615.600 us; speedup vs baseline: 3.9926x; 1.3196x over previous
//
#include <hip/hip_runtime.h>

#define BB 2
#define CIN 256
#define HH 64
#define WW 64
#define NPIX 4096
#define CD 128
#define CO2 256
#define KOUT 19
#define EPSV 1e-5f
#define SPAD 4356   // 66*66 padded spatial
#define KW9 2304    // 256*9

typedef __attribute__((ext_vector_type(8))) short bf16x8;
typedef __attribute__((ext_vector_type(4))) float f32x4;

__device__ inline unsigned short f2bf(float f) {
  unsigned u = __float_as_uint(f);
  u += 0x7fffu + ((u >> 16) & 1u);   // RNE
  return (unsigned short)(u >> 16);
}
__device__ inline void f2bf_pair(float f, unsigned short& hi, unsigned short& lo) {
  hi = f2bf(f);
  const float fhi = __uint_as_float((unsigned)hi << 16);
  lo = f2bf(f - fhi);
}

// ---------------------------------------------------------------------------
// zero-fill xT_hi and xT_lo (2 * 2,230,272 bf16 = 557,568 uint4)
__global__ __launch_bounds__(256) void zfill_kernel(uint4* __restrict__ p)
{
  const int i = blockIdx.x * 256 + threadIdx.x;
  if (i < 557568) p[i] = make_uint4(0, 0, 0, 0);
}

// Transpose+pad: xT[b][(y+1)*66+(x+1)][ci] (hi/lo bf16) from x[b][ci][y*64+x].
__global__ __launch_bounds__(256) void xpose_kernel(
    const float* __restrict__ x, unsigned short* __restrict__ xThi,
    unsigned short* __restrict__ xTlo)
{
  const int y = blockIdx.x;
  const int cig = blockIdx.y;
  const int b = blockIdx.z;
  __shared__ float Tl[32][65];
  const int t = threadIdx.x;
  {
    const int cl = t >> 3, pg = t & 7;
    const float* src = x + ((size_t)(b * CIN + cig * 32 + cl)) * NPIX + y * 64 + pg * 8;
    const float4 v0 = *reinterpret_cast<const float4*>(src);
    const float4 v1 = *reinterpret_cast<const float4*>(src + 4);
    Tl[cl][pg * 8 + 0] = v0.x; Tl[cl][pg * 8 + 1] = v0.y;
    Tl[cl][pg * 8 + 2] = v0.z; Tl[cl][pg * 8 + 3] = v0.w;
    Tl[cl][pg * 8 + 4] = v1.x; Tl[cl][pg * 8 + 5] = v1.y;
    Tl[cl][pg * 8 + 6] = v1.z; Tl[cl][pg * 8 + 7] = v1.w;
  }
  __syncthreads();
  {
    const int sl = t >> 2, cg = t & 3;
    unsigned short hh[8], ll[8];
    #pragma unroll
    for (int i = 0; i < 8; ++i) f2bf_pair(Tl[cg * 8 + i][sl], hh[i], ll[i]);
    uint4 ph, pl;
    ph.x = (unsigned)hh[0] | ((unsigned)hh[1] << 16);
    ph.y = (unsigned)hh[2] | ((unsigned)hh[3] << 16);
    ph.z = (unsigned)hh[4] | ((unsigned)hh[5] << 16);
    ph.w = (unsigned)hh[6] | ((unsigned)hh[7] << 16);
    pl.x = (unsigned)ll[0] | ((unsigned)ll[1] << 16);
    pl.y = (unsigned)ll[2] | ((unsigned)ll[3] << 16);
    pl.z = (unsigned)ll[4] | ((unsigned)ll[5] << 16);
    pl.w = (unsigned)ll[6] | ((unsigned)ll[7] << 16);
    const size_t o = ((size_t)b * SPAD + (y + 1) * 66 + 1 + sl) * 256 + cig * 32 + cg * 8;
    *reinterpret_cast<uint4*>(&xThi[o]) = ph;
    *reinterpret_cast<uint4*>(&xTlo[o]) = pl;
  }
}

// Weights: wb[co][q][ci] hi/lo from w[co][ci][3][3].
__global__ __launch_bounds__(256) void wbconv_kernel(
    const float* __restrict__ w_pam, const float* __restrict__ w_cam,
    unsigned short* __restrict__ wbhi, unsigned short* __restrict__ wblo)
{
  const int co = blockIdx.x;
  const float* wsrc = (co < CD) ? (w_pam + (size_t)co * KW9)
                                : (w_cam + (size_t)(co - CD) * KW9);
  const int t = threadIdx.x;
  #pragma unroll
  for (int i = 0; i < 9; ++i) {
    const int idx = i * 256 + t;
    const int q = idx >> 8, ci = idx & 255;
    unsigned short h, l;
    f2bf_pair(wsrc[ci * 9 + q], h, l);
    wbhi[(size_t)co * KW9 + idx] = h;
    wblo[(size_t)co * KW9 + idx] = l;
  }
}

// Implicit-GEMM conv3x3 via split-bf16 MFMA (fp32-equivalent precision).
__global__ __launch_bounds__(64) void conv_mfma_kernel(
    const unsigned short* __restrict__ xThi, const unsigned short* __restrict__ xTlo,
    const unsigned short* __restrict__ wbhi, const unsigned short* __restrict__ wblo,
    float* __restrict__ out)
{
  const int pxt = blockIdx.x;
  const int cot = blockIdx.y;
  const int b = blockIdx.z;
  const int lane = threadIdx.x;
  const int m = lane & 15, g = lane >> 4;
  const int p0 = pxt * 32;
  const int y = p0 >> 6, x0 = p0 & 63;
  const int sbase = (y + 1) * 66 + (x0 + 1);
  const int co0 = cot * 128;

  const size_t xb = (size_t)b * SPAD * 256;

  f32x4 acc[8][2];
  #pragma unroll
  for (int mt = 0; mt < 8; ++mt)
    #pragma unroll
    for (int jt = 0; jt < 2; ++jt)
      #pragma unroll
      for (int r = 0; r < 4; ++r) acc[mt][jt][r] = 0.f;

  for (int q = 0; q < 9; ++q) {
    const int dq = (q / 3 - 1) * 66 + (q % 3 - 1);
    const unsigned short* xh0 = xThi + xb + (size_t)(sbase + m + dq) * 256;
    const unsigned short* xl0 = xTlo + xb + (size_t)(sbase + m + dq) * 256;
    const unsigned short* wh = wbhi + (size_t)(co0 + m) * KW9 + q * 256;
    const unsigned short* wl = wblo + (size_t)(co0 + m) * KW9 + q * 256;
    #pragma unroll
    for (int kk = 0; kk < 8; ++kk) {
      const int ko = kk * 32 + g * 8;
      const bf16x8 bh0 = *reinterpret_cast<const bf16x8*>(&xh0[ko]);
      const bf16x8 bl0 = *reinterpret_cast<const bf16x8*>(&xl0[ko]);
      const bf16x8 bh1 = *reinterpret_cast<const bf16x8*>(&xh0[16 * 256 + ko]);
      const bf16x8 bl1 = *reinterpret_cast<const bf16x8*>(&xl0[16 * 256 + ko]);
      #pragma unroll
      for (int mt = 0; mt < 8; ++mt) {
        const bf16x8 ah = *reinterpret_cast<const bf16x8*>(&wh[(size_t)mt * 16 * KW9 + ko]);
        const bf16x8 al = *reinterpret_cast<const bf16x8*>(&wl[(size_t)mt * 16 * KW9 + ko]);
        acc[mt][0] = __builtin_amdgcn_mfma_f32_16x16x32_bf16(ah, bh0, acc[mt][0], 0, 0, 0);
        acc[mt][1] = __builtin_amdgcn_mfma_f32_16x16x32_bf16(ah, bh1, acc[mt][1], 0, 0, 0);
        acc[mt][0] = __builtin_amdgcn_mfma_f32_16x16x32_bf16(ah, bl0, acc[mt][0], 0, 0, 0);
        acc[mt][1] = __builtin_amdgcn_mfma_f32_16x16x32_bf16(ah, bl1, acc[mt][1], 0, 0, 0);
        acc[mt][0] = __builtin_amdgcn_mfma_f32_16x16x32_bf16(al, bh0, acc[mt][0], 0, 0, 0);
        acc[mt][1] = __builtin_amdgcn_mfma_f32_16x16x32_bf16(al, bh1, acc[mt][1], 0, 0, 0);
      }
    }
  }

  #pragma unroll
  for (int mt = 0; mt < 8; ++mt)
    #pragma unroll
    for (int r = 0; r < 4; ++r) {
      const int co = co0 + mt * 16 + g * 4 + r;
      float* op = out + ((size_t)b * CO2 + co) * NPIX + p0 + m;
      op[0] = acc[mt][0][r];
      op[16] = acc[mt][1][r];
    }
}

// ---------------------------------------------------------------------------
__global__ __launch_bounds__(256) void gn_stats_kernel(
    const float* __restrict__ conv, float* __restrict__ meanb, float* __restrict__ rstdb)
{
  const int g = blockIdx.x;
  const float* base = conv + (size_t)g * (4 * NPIX);
  float s = 0.f, ss = 0.f;
  const float4* b4 = reinterpret_cast<const float4*>(base);
  for (int i = threadIdx.x; i < 4096; i += 256) {
    float4 v = b4[i];
    s += v.x + v.y + v.z + v.w;
    ss += v.x * v.x + v.y * v.y + v.z * v.z + v.w * v.w;
  }
  #pragma unroll
  for (int off = 32; off > 0; off >>= 1) {
    s += __shfl_down(s, off);
    ss += __shfl_down(ss, off);
  }
  __shared__ float rs[4], rss[4];
  const int lane = threadIdx.x & 63, wv = threadIdx.x >> 6;
  if (lane == 0) { rs[wv] = s; rss[wv] = ss; }
  __syncthreads();
  if (threadIdx.x == 0) {
    const float S = rs[0] + rs[1] + rs[2] + rs[3];
    const float SS = rss[0] + rss[1] + rss[2] + rss[3];
    const float inv = 1.f / 16384.f;
    const float m = S * inv;
    const float var = SS * inv - m * m;
    meanb[g] = m;
    rstdb[g] = rsqrtf(var + EPSV);
  }
}

__global__ __launch_bounds__(256) void gn_apply_kernel(
    float* __restrict__ conv, const float* __restrict__ meanb, const float* __restrict__ rstdb,
    const float* __restrict__ sc_pam, const float* __restrict__ bi_pam,
    const float* __restrict__ sc_cam, const float* __restrict__ bi_cam)
{
  const int idx = blockIdx.x * 256 + threadIdx.x;
  const int call = (idx >> 12) & 255;
  const int g = idx >> 14;
  const int head = call >> 7;
  const int c = call & 127;
  const float sc = head ? sc_cam[c] : sc_pam[c];
  const float bi = head ? bi_cam[c] : bi_pam[c];
  const float v = conv[idx];
  const float r = (v - meanb[g]) * rstdb[g] * sc + bi;
  conv[idx] = fmaxf(r, 0.f);
}

// ---------------------------------------------------------------------------
// bf16 copies of the PAM half: Pb[c][px] and Pt[px][c].
__global__ __launch_bounds__(256) void to_bf16_kernel(
    const float* __restrict__ conv, unsigned short* __restrict__ Pb,
    unsigned short* __restrict__ Pt)
{
  const int px0 = blockIdx.x * 64;
  const int c0  = blockIdx.y * 32;
  const int b   = blockIdx.z;
  __shared__ unsigned short Tl[32][76];
  const int t = threadIdx.x;
  {
    const int cl = t >> 3, pg = t & 7;
    const float* src = conv + ((size_t)b * CO2 + c0 + cl) * NPIX + px0 + pg * 8;
    const float4 v0 = *reinterpret_cast<const float4*>(src);
    const float4 v1 = *reinterpret_cast<const float4*>(src + 4);
    unsigned short h0 = f2bf(v0.x), h1 = f2bf(v0.y), h2 = f2bf(v0.z), h3 = f2bf(v0.w);
    unsigned short h4 = f2bf(v1.x), h5 = f2bf(v1.y), h6 = f2bf(v1.z), h7 = f2bf(v1.w);
    uint4 packed;
    packed.x = (unsigned)h0 | ((unsigned)h1 << 16);
    packed.y = (unsigned)h2 | ((unsigned)h3 << 16);
    packed.z = (unsigned)h4 | ((unsigned)h5 << 16);
    packed.w = (unsigned)h6 | ((unsigned)h7 << 16);
    unsigned short* dst = Pb + ((size_t)b * CD + c0 + cl) * NPIX + px0 + pg * 8;
    *reinterpret_cast<uint4*>(dst) = packed;
    Tl[cl][pg * 8 + 0] = h0; Tl[cl][pg * 8 + 1] = h1;
    Tl[cl][pg * 8 + 2] = h2; Tl[cl][pg * 8 + 3] = h3;
    Tl[cl][pg * 8 + 4] = h4; Tl[cl][pg * 8 + 5] = h5;
    Tl[cl][pg * 8 + 6] = h6; Tl[cl][pg * 8 + 7] = h7;
  }
  __syncthreads();
  {
    const int pl = t >> 2, cg = t & 3;
    unsigned short h[8];
    #pragma unroll
    for (int i = 0; i < 8; ++i) h[i] = Tl[cg * 8 + i][pl];
    uint4 packed;
    packed.x = (unsigned)h[0] | ((unsigned)h[1] << 16);
    packed.y = (unsigned)h[2] | ((unsigned)h[3] << 16);
    packed.z = (unsigned)h[4] | ((unsigned)h[5] << 16);
    packed.w = (unsigned)h[6] | ((unsigned)h[7] << 16);
    unsigned short* dst = Pt + ((size_t)b * NPIX + px0 + pl) * CD + c0 + cg * 8;
    *reinterpret_cast<uint4*>(dst) = packed;
  }
}

// ---------------------------------------------------------------------------
// PAM flash attention via bf16 MFMA (round-6 passing version).
__global__ __launch_bounds__(64) void pam_mfma_kernel(
    const float* __restrict__ conv, const unsigned short* __restrict__ Pb,
    const unsigned short* __restrict__ Pt, float* __restrict__ spam)
{
  const int b = blockIdx.y;
  const int q0 = blockIdx.x * 16;
  const int lane = threadIdx.x;
  const int m = lane & 15, g = lane >> 4;

  __shared__ __align__(16) unsigned short Sl[16 * 88];

  const unsigned short* PtB = Pt + (size_t)b * NPIX * CD;
  const unsigned short* PbB = Pb + (size_t)b * CD * NPIX;

  bf16x8 qf[4];
  #pragma unroll
  for (int kk = 0; kk < 4; ++kk)
    qf[kk] = *reinterpret_cast<const bf16x8*>(&PtB[(q0 + m) * CD + kk * 32 + g * 8]);

  f32x4 oacc[8];
  #pragma unroll
  for (int ct = 0; ct < 8; ++ct)
    #pragma unroll
    for (int r = 0; r < 4; ++r) oacc[ct][r] = 0.f;

  float mrow[4] = {-1e30f, -1e30f, -1e30f, -1e30f};
  float lrow[4] = {0.f, 0.f, 0.f, 0.f};

  for (int t = 0; t < NPIX / 64; ++t) {
    const int j0 = t * 64;
    f32x4 sacc[4];
    #pragma unroll
    for (int jt = 0; jt < 4; ++jt)
      #pragma unroll
      for (int r = 0; r < 4; ++r) sacc[jt][r] = 0.f;
    #pragma unroll
    for (int jt = 0; jt < 4; ++jt) {
      #pragma unroll
      for (int kk = 0; kk < 4; ++kk) {
        const bf16x8 kf = *reinterpret_cast<const bf16x8*>(
            &PtB[(j0 + jt * 16 + m) * CD + kk * 32 + g * 8]);
        sacc[jt] = __builtin_amdgcn_mfma_f32_16x16x32_bf16(qf[kk], kf, sacc[jt], 0, 0, 0);
      }
    }
    float fac[4];
    #pragma unroll
    for (int r = 0; r < 4; ++r) {
      float v = fmaxf(fmaxf(sacc[0][r], sacc[1][r]), fmaxf(sacc[2][r], sacc[3][r]));
      v = fmaxf(v, __shfl_xor(v, 1));
      v = fmaxf(v, __shfl_xor(v, 2));
      v = fmaxf(v, __shfl_xor(v, 4));
      v = fmaxf(v, __shfl_xor(v, 8));
      const float mn = fmaxf(mrow[r], v);
      fac[r] = __expf(fmaxf(mrow[r] - mn, -80.f));
      mrow[r] = mn;
    }
    #pragma unroll
    for (int r = 0; r < 4; ++r) {
      float ls = 0.f;
      #pragma unroll
      for (int jt = 0; jt < 4; ++jt) {
        const float e = __expf(sacc[jt][r] - mrow[r]);
        ls += e;
        Sl[(g * 4 + r) * 88 + jt * 16 + m] = f2bf(e);
      }
      ls += __shfl_xor(ls, 1);
      ls += __shfl_xor(ls, 2);
      ls += __shfl_xor(ls, 4);
      ls += __shfl_xor(ls, 8);
      lrow[r] = lrow[r] * fac[r] + ls;
    }
    const int sel = m & 3;
    float fsel = (sel == 0) ? fac[0] : (sel == 1) ? fac[1] : (sel == 2) ? fac[2] : fac[3];
    const float facq = __shfl(fsel, ((m >> 2) << 4) | sel);
    #pragma unroll
    for (int ct = 0; ct < 8; ++ct)
      #pragma unroll
      for (int r = 0; r < 4; ++r) oacc[ct][r] *= facq;
    bf16x8 pf[2];
    #pragma unroll
    for (int kt = 0; kt < 2; ++kt)
      pf[kt] = *reinterpret_cast<const bf16x8*>(&Sl[m * 88 + kt * 32 + g * 8]);
    #pragma unroll
    for (int ct = 0; ct < 8; ++ct) {
      #pragma unroll
      for (int kt = 0; kt < 2; ++kt) {
        const bf16x8 vf = *reinterpret_cast<const bf16x8*>(
            &PbB[(ct * 16 + m) * (size_t)NPIX + j0 + kt * 32 + g * 8]);
        oacc[ct] = __builtin_amdgcn_mfma_f32_16x16x32_bf16(vf, pf[kt], oacc[ct], 0, 0, 0);
      }
    }
  }

  const int sel = m & 3;
  float lsel = (sel == 0) ? lrow[0] : (sel == 1) ? lrow[1] : (sel == 2) ? lrow[2] : lrow[3];
  const float lq = __shfl(lsel, ((m >> 2) << 4) | sel);
  const float inv = 1.f / lq;
  #pragma unroll
  for (int ct = 0; ct < 8; ++ct) {
    #pragma unroll
    for (int r = 0; r < 4; ++r) {
      const int c = ct * 16 + g * 4 + r;
      const size_t o = ((size_t)b * CD + c) * NPIX + q0 + m;
      spam[o] = conv[((size_t)b * CO2 + c) * NPIX + q0 + m] + oacc[ct][r] * inv;
    }
  }
}

// ---------------------------------------------------------------------------
__global__ __launch_bounds__(128) void cam_gram_naive_kernel(
    const float* __restrict__ conv, float* __restrict__ graw)
{
  const int bc = blockIdx.x;
  const int b = bc >> 7, c = bc & 127;
  const int d = threadIdx.x;
  const float* Am = conv + ((size_t)b * CO2 + CD) * NPIX;
  const float* rc = Am + (size_t)c * NPIX;
  const float* rd = Am + (size_t)d * NPIX;
  float acc = 0.f;
  for (int n = 0; n < NPIX; ++n) acc += rc[n] * rd[n];
  graw[(size_t)bc * CD + d] = acc;
}

__global__ __launch_bounds__(128) void cam_softmax_kernel(
    const float* __restrict__ graw, float* __restrict__ camw)
{
  const int bc = blockIdx.x;
  const int d = threadIdx.x;
  const float g = graw[(size_t)bc * CD + d];
  float m = g;
  #pragma unroll
  for (int off = 32; off > 0; off >>= 1) m = fmaxf(m, __shfl_xor(m, off));
  __shared__ float sm[2], ssum[2];
  const int lane = d & 63, wv = d >> 6;
  if (lane == 0) sm[wv] = m;
  __syncthreads();
  m = fmaxf(sm[0], sm[1]);
  const float e = __expf(g - m);
  float s = e;
  #pragma unroll
  for (int off = 32; off > 0; off >>= 1) s += __shfl_xor(s, off);
  if (lane == 0) ssum[wv] = s;
  __syncthreads();
  camw[(size_t)bc * CD + d] = e / (ssum[0] + ssum[1]);
}

__global__ __launch_bounds__(256) void cam_apply_naive_kernel(
    const float* __restrict__ conv, const float* __restrict__ camw, float* __restrict__ scam)
{
  const int n = blockIdx.x * 256 + threadIdx.x;
  const int c = blockIdx.y;
  const int b = blockIdx.z;
  const float* Am = conv + ((size_t)b * CO2 + CD) * NPIX;
  const float* Wr = camw + ((size_t)b * CD + c) * CD;
  float acc = 0.f;
  for (int d = 0; d < CD; ++d)
    acc += Wr[d] * Am[(size_t)d * NPIX + n];
  scam[((size_t)b * CD + c) * NPIX + n] = Am[(size_t)c * NPIX + n] + acc;
}

// ---------------------------------------------------------------------------
__global__ __launch_bounds__(256) void pred_kernel(
    const float* __restrict__ spam, const float* __restrict__ scam,
    const float* __restrict__ wpred, const float* __restrict__ bpred,
    float* __restrict__ logit)
{
  const int b = blockIdx.y;
  const int p = blockIdx.x * 256 + threadIdx.x;
  float acc[KOUT];
  #pragma unroll
  for (int k = 0; k < KOUT; ++k) acc[k] = bpred[k];
  const float* sp = spam + (size_t)b * CD * NPIX + p;
  const float* sc = scam + (size_t)b * CD * NPIX + p;
  for (int c = 0; c < CD; ++c) {
    const float f = sp[(size_t)c * NPIX] + sc[(size_t)c * NPIX];
    #pragma unroll
    for (int k = 0; k < KOUT; ++k)
      acc[k] += f * wpred[k * CD + c];
  }
  #pragma unroll
  for (int k = 0; k < KOUT; ++k)
    logit[((size_t)b * KOUT + k) * NPIX + p] = acc[k];
}

__global__ __launch_bounds__(256) void upsample_kernel(
    const float* __restrict__ logit, float* __restrict__ out)
{
  const int idx = blockIdx.x * 256 + threadIdx.x;
  if (idx >= BB * KOUT * 256 * 256) return;
  const int ox = idx & 255;
  const int oy = (idx >> 8) & 255;
  const int plane = idx >> 16;
  const float* src = logit + (size_t)plane * NPIX;
  const float sy = (oy + 0.5f) * 0.25f - 0.5f;
  const float sx = (ox + 0.5f) * 0.25f - 0.5f;
  const float fyf = floorf(sy), fxf = floorf(sx);
  const float wy = sy - fyf, wx = sx - fxf;
  const int y0 = (int)fyf, x0 = (int)fxf;
  const int y0c = y0 < 0 ? 0 : y0;
  const int y1c = (y0 + 1 > 63) ? 63 : y0 + 1;
  const int x0c = x0 < 0 ? 0 : x0;
  const int x1c = (x0 + 1 > 63) ? 63 : x0 + 1;
  const float v00 = src[y0c * 64 + x0c], v01 = src[y0c * 64 + x1c];
  const float v10 = src[y1c * 64 + x0c], v11 = src[y1c * 64 + x1c];
  const float top = v00 + (v01 - v00) * wx;
  const float bot = v10 + (v11 - v10) * wx;
  out[idx] = top + (bot - top) * wy;
}

// ---------------------------------------------------------------------------
extern "C" void kernel_launch(void* const* d_in, const int* in_sizes, int n_in,
                              void* d_out, int out_size, void* d_ws, size_t ws_size,
                              hipStream_t stream) {
  (void)in_sizes; (void)n_in; (void)out_size; (void)ws_size;
  const float* x      = (const float*)d_in[0];
  const float* w_pam  = (const float*)d_in[1];
  const float* s_pam  = (const float*)d_in[2];
  const float* b_pam  = (const float*)d_in[3];
  const float* w_cam  = (const float*)d_in[4];
  const float* s_cam  = (const float*)d_in[5];
  const float* b_cam  = (const float*)d_in[6];
  const float* w_pred = (const float*)d_in[7];
  const float* b_pred = (const float*)d_in[8];
  float* out_f = (float*)d_out;
  float* ws0 = (float*)d_ws;

  // workspace layout (floats), total 5,138,688 = 20.55 MB
  // conv   [0,          2,097,152)
  // xThi   [2,097,152,  3,212,288)  = 2,230,272 bf16 (BB*SPAD*256)
  // xTlo   [3,212,288,  4,327,424)  = 2,230,272 bf16
  // wbhi   [4,327,424,  4,622,336)  =   589,824 bf16 (CO2*KW9)
  // wblo   [4,622,336,  4,917,248)  =   589,824 bf16
  // graw   [4,917,248,  4,950,016)
  // camw   [4,950,016,  4,982,784)
  // meanb  [4,982,784,  4,982,912)
  // rstdb  [4,982,912,  4,983,040)
  // logit  [4,983,040,  5,138,688)
  float* conv  = ws0;
  unsigned short* xThi = (unsigned short*)(ws0 + 2097152);
  unsigned short* xTlo = xThi + (size_t)BB * SPAD * 256;     // +2,230,272 shorts
  unsigned short* wbhi = (unsigned short*)(ws0 + 4327424);   // AFTER full xT pair
  unsigned short* wblo = wbhi + (size_t)CO2 * KW9;           // +589,824 shorts
  float* graw  = ws0 + 4917248;
  float* camw  = ws0 + 4950016;
  float* meanb = ws0 + 4982784;
  float* rstdb = ws0 + 4982912;
  float* logit = ws0 + 4983040;

  // Pb/Pt reuse the xT region (xT dead after conv_mfma; Pb/Pt written later).
  unsigned short* Pb = xThi;          // 1,048,576 bf16
  unsigned short* Pt = Pb + 1048576;  // 1,048,576 bf16

  // d_out doubles as scratch for spam/scam; upsample fully rewrites d_out.
  float* spam = out_f;
  float* scam = out_f + 1048576;

  zfill_kernel<<<2178, 256, 0, stream>>>((uint4*)xThi);   // zeroes xThi+xTlo
  xpose_kernel<<<dim3(64, 8, 2), 256, 0, stream>>>(x, xThi, xTlo);
  wbconv_kernel<<<256, 256, 0, stream>>>(w_pam, w_cam, wbhi, wblo);
  conv_mfma_kernel<<<dim3(128, 2, 2), 64, 0, stream>>>(xThi, xTlo, wbhi, wblo, conv);
  gn_stats_kernel<<<128, 256, 0, stream>>>(conv, meanb, rstdb);
  gn_apply_kernel<<<8192, 256, 0, stream>>>(conv, meanb, rstdb, s_pam, b_pam, s_cam, b_cam);
  to_bf16_kernel<<<dim3(64, 4, 2), 256, 0, stream>>>(conv, Pb, Pt);
  cam_gram_naive_kernel<<<256, 128, 0, stream>>>(conv, graw);
  cam_softmax_kernel<<<256, 128, 0, stream>>>(graw, camw);
  cam_apply_naive_kernel<<<dim3(16, 128, 2), 256, 0, stream>>>(conv, camw, scam);
  pam_mfma_kernel<<<dim3(256, 2), 64, 0, stream>>>(conv, Pb, Pt, spam);
  pred_kernel<<<dim3(16, 2), 256, 0, stream>>>(spam, scam, w_pred, b_pred, logit);
  upsample_kernel<<<9728, 256, 0, stream>>>(logit, out_f);
}

// Round 9
// 478.244 us; speedup vs baseline: 5.1393x; 1.2872x over previous
//
#include <hip/hip_runtime.h>

#define BB 2
#define CIN 256
#define HH 64
#define WW 64
#define NPIX 4096
#define CD 128
#define CO2 256
#define KOUT 19
#define EPSV 1e-5f
#define SPAD 4356   // 66*66 padded spatial
#define KW9 2304    // 256*9

typedef __attribute__((ext_vector_type(8))) short bf16x8;
typedef __attribute__((ext_vector_type(4))) float f32x4;

__device__ inline unsigned short f2bf(float f) {
  unsigned u = __float_as_uint(f);
  u += 0x7fffu + ((u >> 16) & 1u);   // RNE
  return (unsigned short)(u >> 16);
}
__device__ inline void f2bf_pair(float f, unsigned short& hi, unsigned short& lo) {
  hi = f2bf(f);
  const float fhi = __uint_as_float((unsigned)hi << 16);
  lo = f2bf(f - fhi);
}

// ---------------------------------------------------------------------------
// zero-fill xT_hi and xT_lo (2 * 2,230,272 bf16 = 557,568 uint4)
__global__ __launch_bounds__(256) void zfill_kernel(uint4* __restrict__ p)
{
  const int i = blockIdx.x * 256 + threadIdx.x;
  if (i < 557568) p[i] = make_uint4(0, 0, 0, 0);
}

// Transpose+pad: xT[b][(y+1)*66+(x+1)][ci] (hi/lo bf16) from x[b][ci][y*64+x].
__global__ __launch_bounds__(256) void xpose_kernel(
    const float* __restrict__ x, unsigned short* __restrict__ xThi,
    unsigned short* __restrict__ xTlo)
{
  const int y = blockIdx.x;
  const int cig = blockIdx.y;
  const int b = blockIdx.z;
  __shared__ float Tl[32][65];
  const int t = threadIdx.x;
  {
    const int cl = t >> 3, pg = t & 7;
    const float* src = x + ((size_t)(b * CIN + cig * 32 + cl)) * NPIX + y * 64 + pg * 8;
    const float4 v0 = *reinterpret_cast<const float4*>(src);
    const float4 v1 = *reinterpret_cast<const float4*>(src + 4);
    Tl[cl][pg * 8 + 0] = v0.x; Tl[cl][pg * 8 + 1] = v0.y;
    Tl[cl][pg * 8 + 2] = v0.z; Tl[cl][pg * 8 + 3] = v0.w;
    Tl[cl][pg * 8 + 4] = v1.x; Tl[cl][pg * 8 + 5] = v1.y;
    Tl[cl][pg * 8 + 6] = v1.z; Tl[cl][pg * 8 + 7] = v1.w;
  }
  __syncthreads();
  {
    const int sl = t >> 2, cg = t & 3;
    unsigned short hh[8], ll[8];
    #pragma unroll
    for (int i = 0; i < 8; ++i) f2bf_pair(Tl[cg * 8 + i][sl], hh[i], ll[i]);
    uint4 ph, pl;
    ph.x = (unsigned)hh[0] | ((unsigned)hh[1] << 16);
    ph.y = (unsigned)hh[2] | ((unsigned)hh[3] << 16);
    ph.z = (unsigned)hh[4] | ((unsigned)hh[5] << 16);
    ph.w = (unsigned)hh[6] | ((unsigned)hh[7] << 16);
    pl.x = (unsigned)ll[0] | ((unsigned)ll[1] << 16);
    pl.y = (unsigned)ll[2] | ((unsigned)ll[3] << 16);
    pl.z = (unsigned)ll[4] | ((unsigned)ll[5] << 16);
    pl.w = (unsigned)ll[6] | ((unsigned)ll[7] << 16);
    const size_t o = ((size_t)b * SPAD + (y + 1) * 66 + 1 + sl) * 256 + cig * 32 + cg * 8;
    *reinterpret_cast<uint4*>(&xThi[o]) = ph;
    *reinterpret_cast<uint4*>(&xTlo[o]) = pl;
  }
}

// Weights: wb[co][q][ci] hi/lo from w[co][ci][3][3].
__global__ __launch_bounds__(256) void wbconv_kernel(
    const float* __restrict__ w_pam, const float* __restrict__ w_cam,
    unsigned short* __restrict__ wbhi, unsigned short* __restrict__ wblo)
{
  const int co = blockIdx.x;
  const float* wsrc = (co < CD) ? (w_pam + (size_t)co * KW9)
                                : (w_cam + (size_t)(co - CD) * KW9);
  const int t = threadIdx.x;
  #pragma unroll
  for (int i = 0; i < 9; ++i) {
    const int idx = i * 256 + t;
    const int q = idx >> 8, ci = idx & 255;
    unsigned short h, l;
    f2bf_pair(wsrc[ci * 9 + q], h, l);
    wbhi[(size_t)co * KW9 + idx] = h;
    wblo[(size_t)co * KW9 + idx] = l;
  }
}

// Implicit-GEMM conv3x3 via split-bf16 MFMA (fp32-equivalent precision).
__global__ __launch_bounds__(64) void conv_mfma_kernel(
    const unsigned short* __restrict__ xThi, const unsigned short* __restrict__ xTlo,
    const unsigned short* __restrict__ wbhi, const unsigned short* __restrict__ wblo,
    float* __restrict__ out)
{
  const int pxt = blockIdx.x;
  const int cot = blockIdx.y;
  const int b = blockIdx.z;
  const int lane = threadIdx.x;
  const int m = lane & 15, g = lane >> 4;
  const int p0 = pxt * 32;
  const int y = p0 >> 6, x0 = p0 & 63;
  const int sbase = (y + 1) * 66 + (x0 + 1);
  const int co0 = cot * 128;

  const size_t xb = (size_t)b * SPAD * 256;

  f32x4 acc[8][2];
  #pragma unroll
  for (int mt = 0; mt < 8; ++mt)
    #pragma unroll
    for (int jt = 0; jt < 2; ++jt)
      #pragma unroll
      for (int r = 0; r < 4; ++r) acc[mt][jt][r] = 0.f;

  for (int q = 0; q < 9; ++q) {
    const int dq = (q / 3 - 1) * 66 + (q % 3 - 1);
    const unsigned short* xh0 = xThi + xb + (size_t)(sbase + m + dq) * 256;
    const unsigned short* xl0 = xTlo + xb + (size_t)(sbase + m + dq) * 256;
    const unsigned short* wh = wbhi + (size_t)(co0 + m) * KW9 + q * 256;
    const unsigned short* wl = wblo + (size_t)(co0 + m) * KW9 + q * 256;
    #pragma unroll
    for (int kk = 0; kk < 8; ++kk) {
      const int ko = kk * 32 + g * 8;
      const bf16x8 bh0 = *reinterpret_cast<const bf16x8*>(&xh0[ko]);
      const bf16x8 bl0 = *reinterpret_cast<const bf16x8*>(&xl0[ko]);
      const bf16x8 bh1 = *reinterpret_cast<const bf16x8*>(&xh0[16 * 256 + ko]);
      const bf16x8 bl1 = *reinterpret_cast<const bf16x8*>(&xl0[16 * 256 + ko]);
      #pragma unroll
      for (int mt = 0; mt < 8; ++mt) {
        const bf16x8 ah = *reinterpret_cast<const bf16x8*>(&wh[(size_t)mt * 16 * KW9 + ko]);
        const bf16x8 al = *reinterpret_cast<const bf16x8*>(&wl[(size_t)mt * 16 * KW9 + ko]);
        acc[mt][0] = __builtin_amdgcn_mfma_f32_16x16x32_bf16(ah, bh0, acc[mt][0], 0, 0, 0);
        acc[mt][1] = __builtin_amdgcn_mfma_f32_16x16x32_bf16(ah, bh1, acc[mt][1], 0, 0, 0);
        acc[mt][0] = __builtin_amdgcn_mfma_f32_16x16x32_bf16(ah, bl0, acc[mt][0], 0, 0, 0);
        acc[mt][1] = __builtin_amdgcn_mfma_f32_16x16x32_bf16(ah, bl1, acc[mt][1], 0, 0, 0);
        acc[mt][0] = __builtin_amdgcn_mfma_f32_16x16x32_bf16(al, bh0, acc[mt][0], 0, 0, 0);
        acc[mt][1] = __builtin_amdgcn_mfma_f32_16x16x32_bf16(al, bh1, acc[mt][1], 0, 0, 0);
      }
    }
  }

  #pragma unroll
  for (int mt = 0; mt < 8; ++mt)
    #pragma unroll
    for (int r = 0; r < 4; ++r) {
      const int co = co0 + mt * 16 + g * 4 + r;
      float* op = out + ((size_t)b * CO2 + co) * NPIX + p0 + m;
      op[0] = acc[mt][0][r];
      op[16] = acc[mt][1][r];
    }
}

// ---------------------------------------------------------------------------
__global__ __launch_bounds__(256) void gn_stats_kernel(
    const float* __restrict__ conv, float* __restrict__ meanb, float* __restrict__ rstdb)
{
  const int g = blockIdx.x;
  const float* base = conv + (size_t)g * (4 * NPIX);
  float s = 0.f, ss = 0.f;
  const float4* b4 = reinterpret_cast<const float4*>(base);
  for (int i = threadIdx.x; i < 4096; i += 256) {
    float4 v = b4[i];
    s += v.x + v.y + v.z + v.w;
    ss += v.x * v.x + v.y * v.y + v.z * v.z + v.w * v.w;
  }
  #pragma unroll
  for (int off = 32; off > 0; off >>= 1) {
    s += __shfl_down(s, off);
    ss += __shfl_down(ss, off);
  }
  __shared__ float rs[4], rss[4];
  const int lane = threadIdx.x & 63, wv = threadIdx.x >> 6;
  if (lane == 0) { rs[wv] = s; rss[wv] = ss; }
  __syncthreads();
  if (threadIdx.x == 0) {
    const float S = rs[0] + rs[1] + rs[2] + rs[3];
    const float SS = rss[0] + rss[1] + rss[2] + rss[3];
    const float inv = 1.f / 16384.f;
    const float m = S * inv;
    const float var = SS * inv - m * m;
    meanb[g] = m;
    rstdb[g] = rsqrtf(var + EPSV);
  }
}

__global__ __launch_bounds__(256) void gn_apply_kernel(
    float* __restrict__ conv, const float* __restrict__ meanb, const float* __restrict__ rstdb,
    const float* __restrict__ sc_pam, const float* __restrict__ bi_pam,
    const float* __restrict__ sc_cam, const float* __restrict__ bi_cam)
{
  const int idx = blockIdx.x * 256 + threadIdx.x;
  const int call = (idx >> 12) & 255;
  const int g = idx >> 14;
  const int head = call >> 7;
  const int c = call & 127;
  const float sc = head ? sc_cam[c] : sc_pam[c];
  const float bi = head ? bi_cam[c] : bi_pam[c];
  const float v = conv[idx];
  const float r = (v - meanb[g]) * rstdb[g] * sc + bi;
  conv[idx] = fmaxf(r, 0.f);
}

// ---------------------------------------------------------------------------
// bf16 copies of the PAM half: Pb[c][px] and Pt[px][c].
__global__ __launch_bounds__(256) void to_bf16_kernel(
    const float* __restrict__ conv, unsigned short* __restrict__ Pb,
    unsigned short* __restrict__ Pt)
{
  const int px0 = blockIdx.x * 64;
  const int c0  = blockIdx.y * 32;
  const int b   = blockIdx.z;
  __shared__ unsigned short Tl[32][76];
  const int t = threadIdx.x;
  {
    const int cl = t >> 3, pg = t & 7;
    const float* src = conv + ((size_t)b * CO2 + c0 + cl) * NPIX + px0 + pg * 8;
    const float4 v0 = *reinterpret_cast<const float4*>(src);
    const float4 v1 = *reinterpret_cast<const float4*>(src + 4);
    unsigned short h0 = f2bf(v0.x), h1 = f2bf(v0.y), h2 = f2bf(v0.z), h3 = f2bf(v0.w);
    unsigned short h4 = f2bf(v1.x), h5 = f2bf(v1.y), h6 = f2bf(v1.z), h7 = f2bf(v1.w);
    uint4 packed;
    packed.x = (unsigned)h0 | ((unsigned)h1 << 16);
    packed.y = (unsigned)h2 | ((unsigned)h3 << 16);
    packed.z = (unsigned)h4 | ((unsigned)h5 << 16);
    packed.w = (unsigned)h6 | ((unsigned)h7 << 16);
    unsigned short* dst = Pb + ((size_t)b * CD + c0 + cl) * NPIX + px0 + pg * 8;
    *reinterpret_cast<uint4*>(dst) = packed;
    Tl[cl][pg * 8 + 0] = h0; Tl[cl][pg * 8 + 1] = h1;
    Tl[cl][pg * 8 + 2] = h2; Tl[cl][pg * 8 + 3] = h3;
    Tl[cl][pg * 8 + 4] = h4; Tl[cl][pg * 8 + 5] = h5;
    Tl[cl][pg * 8 + 6] = h6; Tl[cl][pg * 8 + 7] = h7;
  }
  __syncthreads();
  {
    const int pl = t >> 2, cg = t & 3;
    unsigned short h[8];
    #pragma unroll
    for (int i = 0; i < 8; ++i) h[i] = Tl[cg * 8 + i][pl];
    uint4 packed;
    packed.x = (unsigned)h[0] | ((unsigned)h[1] << 16);
    packed.y = (unsigned)h[2] | ((unsigned)h[3] << 16);
    packed.z = (unsigned)h[4] | ((unsigned)h[5] << 16);
    packed.w = (unsigned)h[6] | ((unsigned)h[7] << 16);
    unsigned short* dst = Pt + ((size_t)b * NPIX + px0 + pl) * CD + c0 + cg * 8;
    *reinterpret_cast<uint4*>(dst) = packed;
  }
}

// ---------------------------------------------------------------------------
// PAM flash attention via bf16 MFMA. 4 waves/block, each handles 1024 keys
// for the same 16 queries; LDS merge of (m, l, O) partials at the end.
__global__ __launch_bounds__(256) void pam_mfma_kernel(
    const float* __restrict__ conv, const unsigned short* __restrict__ Pb,
    const unsigned short* __restrict__ Pt, float* __restrict__ spam)
{
  const int b = blockIdx.y;
  const int q0 = blockIdx.x * 16;
  const int tid = threadIdx.x;
  const int w = tid >> 6;            // wave 0..3
  const int lane = tid & 63;
  const int m = lane & 15, g = lane >> 4;

  __shared__ __align__(16) unsigned short Sl[4][16 * 88];
  __shared__ float Obuf[4][16][129];   // [wave][q][c] (+1 pad col)
  __shared__ float mlm[4][16], mll[4][16], ltot[16];

  const unsigned short* PtB = Pt + (size_t)b * NPIX * CD;
  const unsigned short* PbB = Pb + (size_t)b * CD * NPIX;

  bf16x8 qf[4];
  #pragma unroll
  for (int kk = 0; kk < 4; ++kk)
    qf[kk] = *reinterpret_cast<const bf16x8*>(&PtB[(q0 + m) * CD + kk * 32 + g * 8]);

  f32x4 oacc[8];
  #pragma unroll
  for (int ct = 0; ct < 8; ++ct)
    #pragma unroll
    for (int r = 0; r < 4; ++r) oacc[ct][r] = 0.f;

  float mrow[4] = {-1e30f, -1e30f, -1e30f, -1e30f};
  float lrow[4] = {0.f, 0.f, 0.f, 0.f};

  for (int t = w * 16; t < w * 16 + 16; ++t) {
    const int j0 = t * 64;
    f32x4 sacc[4];
    #pragma unroll
    for (int jt = 0; jt < 4; ++jt)
      #pragma unroll
      for (int r = 0; r < 4; ++r) sacc[jt][r] = 0.f;
    #pragma unroll
    for (int jt = 0; jt < 4; ++jt) {
      #pragma unroll
      for (int kk = 0; kk < 4; ++kk) {
        const bf16x8 kf = *reinterpret_cast<const bf16x8*>(
            &PtB[(j0 + jt * 16 + m) * CD + kk * 32 + g * 8]);
        sacc[jt] = __builtin_amdgcn_mfma_f32_16x16x32_bf16(qf[kk], kf, sacc[jt], 0, 0, 0);
      }
    }
    float fac[4];
    #pragma unroll
    for (int r = 0; r < 4; ++r) {
      float v = fmaxf(fmaxf(sacc[0][r], sacc[1][r]), fmaxf(sacc[2][r], sacc[3][r]));
      v = fmaxf(v, __shfl_xor(v, 1));
      v = fmaxf(v, __shfl_xor(v, 2));
      v = fmaxf(v, __shfl_xor(v, 4));
      v = fmaxf(v, __shfl_xor(v, 8));
      const float mn = fmaxf(mrow[r], v);
      fac[r] = __expf(fmaxf(mrow[r] - mn, -80.f));
      mrow[r] = mn;
    }
    #pragma unroll
    for (int r = 0; r < 4; ++r) {
      float ls = 0.f;
      #pragma unroll
      for (int jt = 0; jt < 4; ++jt) {
        const float e = __expf(sacc[jt][r] - mrow[r]);
        ls += e;
        Sl[w][(g * 4 + r) * 88 + jt * 16 + m] = f2bf(e);
      }
      ls += __shfl_xor(ls, 1);
      ls += __shfl_xor(ls, 2);
      ls += __shfl_xor(ls, 4);
      ls += __shfl_xor(ls, 8);
      lrow[r] = lrow[r] * fac[r] + ls;
    }
    const int sel = m & 3;
    float fsel = (sel == 0) ? fac[0] : (sel == 1) ? fac[1] : (sel == 2) ? fac[2] : fac[3];
    const float facq = __shfl(fsel, ((m >> 2) << 4) | sel);
    #pragma unroll
    for (int ct = 0; ct < 8; ++ct)
      #pragma unroll
      for (int r = 0; r < 4; ++r) oacc[ct][r] *= facq;
    bf16x8 pf[2];
    #pragma unroll
    for (int kt = 0; kt < 2; ++kt)
      pf[kt] = *reinterpret_cast<const bf16x8*>(&Sl[w][m * 88 + kt * 32 + g * 8]);
    #pragma unroll
    for (int ct = 0; ct < 8; ++ct) {
      #pragma unroll
      for (int kt = 0; kt < 2; ++kt) {
        const bf16x8 vf = *reinterpret_cast<const bf16x8*>(
            &PbB[(ct * 16 + m) * (size_t)NPIX + j0 + kt * 32 + g * 8]);
        oacc[ct] = __builtin_amdgcn_mfma_f32_16x16x32_bf16(vf, pf[kt], oacc[ct], 0, 0, 0);
      }
    }
  }

  // ---- merge the 4 wave partials ----
  // per-lane m/l for q=m (O^T lane layout) via select + shfl
  const int sel = m & 3;
  float msel_ = (sel == 0) ? mrow[0] : (sel == 1) ? mrow[1] : (sel == 2) ? mrow[2] : mrow[3];
  const float mq = __shfl(msel_, ((m >> 2) << 4) | sel);
  float lsel_ = (sel == 0) ? lrow[0] : (sel == 1) ? lrow[1] : (sel == 2) ? lrow[2] : lrow[3];
  const float lq = __shfl(lsel_, ((m >> 2) << 4) | sel);
  if (g == 0) { mlm[w][m] = mq; mll[w][m] = lq; }
  __syncthreads();
  const float mstar = fmaxf(fmaxf(mlm[0][m], mlm[1][m]), fmaxf(mlm[2][m], mlm[3][m]));
  const float rsw = __expf(fmaxf(mq - mstar, -80.f));
  #pragma unroll
  for (int ct = 0; ct < 8; ++ct)
    #pragma unroll
    for (int r = 0; r < 4; ++r)
      Obuf[w][m][ct * 16 + g * 4 + r] = oacc[ct][r] * rsw;
  if (w == 0 && g == 0) {
    const float lt = mll[0][m] * __expf(fmaxf(mlm[0][m] - mstar, -80.f))
                   + mll[1][m] * __expf(fmaxf(mlm[1][m] - mstar, -80.f))
                   + mll[2][m] * __expf(fmaxf(mlm[2][m] - mstar, -80.f))
                   + mll[3][m] * __expf(fmaxf(mlm[3][m] - mstar, -80.f));
    ltot[m] = lt;
  }
  __syncthreads();
  // cooperative final write: thread -> c = tid>>1, q half = (tid&1)*8
  const int c = tid >> 1;
  const int qh = (tid & 1) * 8;
  const float* cv = conv + ((size_t)b * CO2 + c) * NPIX + q0 + qh;
  float* op = spam + ((size_t)b * CD + c) * NPIX + q0 + qh;
  #pragma unroll
  for (int qq = 0; qq < 8; ++qq) {
    const int ql = qh + qq;
    const float o = Obuf[0][ql][c] + Obuf[1][ql][c] + Obuf[2][ql][c] + Obuf[3][ql][c];
    op[qq] = cv[qq] + o / ltot[ql];
  }
}

// ---------------------------------------------------------------------------
__global__ __launch_bounds__(128) void cam_gram_naive_kernel(
    const float* __restrict__ conv, float* __restrict__ graw)
{
  const int bc = blockIdx.x;
  const int b = bc >> 7, c = bc & 127;
  const int d = threadIdx.x;
  const float* Am = conv + ((size_t)b * CO2 + CD) * NPIX;
  const float* rc = Am + (size_t)c * NPIX;
  const float* rd = Am + (size_t)d * NPIX;
  float acc = 0.f;
  for (int n = 0; n < NPIX; ++n) acc += rc[n] * rd[n];
  graw[(size_t)bc * CD + d] = acc;
}

__global__ __launch_bounds__(128) void cam_softmax_kernel(
    const float* __restrict__ graw, float* __restrict__ camw)
{
  const int bc = blockIdx.x;
  const int d = threadIdx.x;
  const float g = graw[(size_t)bc * CD + d];
  float m = g;
  #pragma unroll
  for (int off = 32; off > 0; off >>= 1) m = fmaxf(m, __shfl_xor(m, off));
  __shared__ float sm[2], ssum[2];
  const int lane = d & 63, wv = d >> 6;
  if (lane == 0) sm[wv] = m;
  __syncthreads();
  m = fmaxf(sm[0], sm[1]);
  const float e = __expf(g - m);
  float s = e;
  #pragma unroll
  for (int off = 32; off > 0; off >>= 1) s += __shfl_xor(s, off);
  if (lane == 0) ssum[wv] = s;
  __syncthreads();
  camw[(size_t)bc * CD + d] = e / (ssum[0] + ssum[1]);
}

__global__ __launch_bounds__(256) void cam_apply_naive_kernel(
    const float* __restrict__ conv, const float* __restrict__ camw, float* __restrict__ scam)
{
  const int n = blockIdx.x * 256 + threadIdx.x;
  const int c = blockIdx.y;
  const int b = blockIdx.z;
  const float* Am = conv + ((size_t)b * CO2 + CD) * NPIX;
  const float* Wr = camw + ((size_t)b * CD + c) * CD;
  float acc = 0.f;
  for (int d = 0; d < CD; ++d)
    acc += Wr[d] * Am[(size_t)d * NPIX + n];
  scam[((size_t)b * CD + c) * NPIX + n] = Am[(size_t)c * NPIX + n] + acc;
}

// ---------------------------------------------------------------------------
__global__ __launch_bounds__(256) void pred_kernel(
    const float* __restrict__ spam, const float* __restrict__ scam,
    const float* __restrict__ wpred, const float* __restrict__ bpred,
    float* __restrict__ logit)
{
  const int b = blockIdx.y;
  const int p = blockIdx.x * 256 + threadIdx.x;
  float acc[KOUT];
  #pragma unroll
  for (int k = 0; k < KOUT; ++k) acc[k] = bpred[k];
  const float* sp = spam + (size_t)b * CD * NPIX + p;
  const float* sc = scam + (size_t)b * CD * NPIX + p;
  for (int c = 0; c < CD; ++c) {
    const float f = sp[(size_t)c * NPIX] + sc[(size_t)c * NPIX];
    #pragma unroll
    for (int k = 0; k < KOUT; ++k)
      acc[k] += f * wpred[k * CD + c];
  }
  #pragma unroll
  for (int k = 0; k < KOUT; ++k)
    logit[((size_t)b * KOUT + k) * NPIX + p] = acc[k];
}

__global__ __launch_bounds__(256) void upsample_kernel(
    const float* __restrict__ logit, float* __restrict__ out)
{
  const int idx = blockIdx.x * 256 + threadIdx.x;
  if (idx >= BB * KOUT * 256 * 256) return;
  const int ox = idx & 255;
  const int oy = (idx >> 8) & 255;
  const int plane = idx >> 16;
  const float* src = logit + (size_t)plane * NPIX;
  const float sy = (oy + 0.5f) * 0.25f - 0.5f;
  const float sx = (ox + 0.5f) * 0.25f - 0.5f;
  const float fyf = floorf(sy), fxf = floorf(sx);
  const float wy = sy - fyf, wx = sx - fxf;
  const int y0 = (int)fyf, x0 = (int)fxf;
  const int y0c = y0 < 0 ? 0 : y0;
  const int y1c = (y0 + 1 > 63) ? 63 : y0 + 1;
  const int x0c = x0 < 0 ? 0 : x0;
  const int x1c = (x0 + 1 > 63) ? 63 : x0 + 1;
  const float v00 = src[y0c * 64 + x0c], v01 = src[y0c * 64 + x1c];
  const float v10 = src[y1c * 64 + x0c], v11 = src[y1c * 64 + x1c];
  const float top = v00 + (v01 - v00) * wx;
  const float bot = v10 + (v11 - v10) * wx;
  out[idx] = top + (bot - top) * wy;
}

// ---------------------------------------------------------------------------
extern "C" void kernel_launch(void* const* d_in, const int* in_sizes, int n_in,
                              void* d_out, int out_size, void* d_ws, size_t ws_size,
                              hipStream_t stream) {
  (void)in_sizes; (void)n_in; (void)out_size; (void)ws_size;
  const float* x      = (const float*)d_in[0];
  const float* w_pam  = (const float*)d_in[1];
  const float* s_pam  = (const float*)d_in[2];
  const float* b_pam  = (const float*)d_in[3];
  const float* w_cam  = (const float*)d_in[4];
  const float* s_cam  = (const float*)d_in[5];
  const float* b_cam  = (const float*)d_in[6];
  const float* w_pred = (const float*)d_in[7];
  const float* b_pred = (const float*)d_in[8];
  float* out_f = (float*)d_out;
  float* ws0 = (float*)d_ws;

  // workspace layout (floats), total 5,138,688 = 20.55 MB (same as round 8)
  float* conv  = ws0;
  unsigned short* xThi = (unsigned short*)(ws0 + 2097152);
  unsigned short* xTlo = xThi + (size_t)BB * SPAD * 256;
  unsigned short* wbhi = (unsigned short*)(ws0 + 4327424);
  unsigned short* wblo = wbhi + (size_t)CO2 * KW9;
  float* graw  = ws0 + 4917248;
  float* camw  = ws0 + 4950016;
  float* meanb = ws0 + 4982784;
  float* rstdb = ws0 + 4982912;
  float* logit = ws0 + 4983040;

  unsigned short* Pb = xThi;
  unsigned short* Pt = Pb + 1048576;

  float* spam = out_f;
  float* scam = out_f + 1048576;

  zfill_kernel<<<2178, 256, 0, stream>>>((uint4*)xThi);
  xpose_kernel<<<dim3(64, 8, 2), 256, 0, stream>>>(x, xThi, xTlo);
  wbconv_kernel<<<256, 256, 0, stream>>>(w_pam, w_cam, wbhi, wblo);
  conv_mfma_kernel<<<dim3(128, 2, 2), 64, 0, stream>>>(xThi, xTlo, wbhi, wblo, conv);
  gn_stats_kernel<<<128, 256, 0, stream>>>(conv, meanb, rstdb);
  gn_apply_kernel<<<8192, 256, 0, stream>>>(conv, meanb, rstdb, s_pam, b_pam, s_cam, b_cam);
  to_bf16_kernel<<<dim3(64, 4, 2), 256, 0, stream>>>(conv, Pb, Pt);
  cam_gram_naive_kernel<<<256, 128, 0, stream>>>(conv, graw);
  cam_softmax_kernel<<<256, 128, 0, stream>>>(graw, camw);
  cam_apply_naive_kernel<<<dim3(16, 128, 2), 256, 0, stream>>>(conv, camw, scam);
  pam_mfma_kernel<<<dim3(256, 2), 256, 0, stream>>>(conv, Pb, Pt, spam);
  pred_kernel<<<dim3(16, 2), 256, 0, stream>>>(spam, scam, w_pred, b_pred, logit);
  upsample_kernel<<<9728, 256, 0, stream>>>(logit, out_f);
}

// Round 10
// 389.541 us; speedup vs baseline: 6.3096x; 1.2277x over previous
//
#include <hip/hip_runtime.h>

#define BB 2
#define CIN 256
#define HH 64
#define WW 64
#define NPIX 4096
#define CD 128
#define CO2 256
#define KOUT 19
#define EPSV 1e-5f
#define SPAD 4356   // 66*66 padded spatial
#define KW9 2304    // 256*9

typedef __attribute__((ext_vector_type(8))) short bf16x8;
typedef __attribute__((ext_vector_type(4))) float f32x4;

__device__ inline unsigned short f2bf(float f) {
  unsigned u = __float_as_uint(f);
  u += 0x7fffu + ((u >> 16) & 1u);   // RNE
  return (unsigned short)(u >> 16);
}
__device__ inline void f2bf_pair(float f, unsigned short& hi, unsigned short& lo) {
  hi = f2bf(f);
  const float fhi = __uint_as_float((unsigned)hi << 16);
  lo = f2bf(f - fhi);
}

// ---------------------------------------------------------------------------
// zero-fill xT_hi and xT_lo (2 * 2,230,272 bf16 = 557,568 uint4)
__global__ __launch_bounds__(256) void zfill_kernel(uint4* __restrict__ p)
{
  const int i = blockIdx.x * 256 + threadIdx.x;
  if (i < 557568) p[i] = make_uint4(0, 0, 0, 0);
}

// Transpose+pad: xT[b][(y+1)*66+(x+1)][ci] (hi/lo bf16) from x[b][ci][y*64+x].
__global__ __launch_bounds__(256) void xpose_kernel(
    const float* __restrict__ x, unsigned short* __restrict__ xThi,
    unsigned short* __restrict__ xTlo)
{
  const int y = blockIdx.x;
  const int cig = blockIdx.y;
  const int b = blockIdx.z;
  __shared__ float Tl[32][65];
  const int t = threadIdx.x;
  {
    const int cl = t >> 3, pg = t & 7;
    const float* src = x + ((size_t)(b * CIN + cig * 32 + cl)) * NPIX + y * 64 + pg * 8;
    const float4 v0 = *reinterpret_cast<const float4*>(src);
    const float4 v1 = *reinterpret_cast<const float4*>(src + 4);
    Tl[cl][pg * 8 + 0] = v0.x; Tl[cl][pg * 8 + 1] = v0.y;
    Tl[cl][pg * 8 + 2] = v0.z; Tl[cl][pg * 8 + 3] = v0.w;
    Tl[cl][pg * 8 + 4] = v1.x; Tl[cl][pg * 8 + 5] = v1.y;
    Tl[cl][pg * 8 + 6] = v1.z; Tl[cl][pg * 8 + 7] = v1.w;
  }
  __syncthreads();
  {
    const int sl = t >> 2, cg = t & 3;
    unsigned short hh[8], ll[8];
    #pragma unroll
    for (int i = 0; i < 8; ++i) f2bf_pair(Tl[cg * 8 + i][sl], hh[i], ll[i]);
    uint4 ph, pl;
    ph.x = (unsigned)hh[0] | ((unsigned)hh[1] << 16);
    ph.y = (unsigned)hh[2] | ((unsigned)hh[3] << 16);
    ph.z = (unsigned)hh[4] | ((unsigned)hh[5] << 16);
    ph.w = (unsigned)hh[6] | ((unsigned)hh[7] << 16);
    pl.x = (unsigned)ll[0] | ((unsigned)ll[1] << 16);
    pl.y = (unsigned)ll[2] | ((unsigned)ll[3] << 16);
    pl.z = (unsigned)ll[4] | ((unsigned)ll[5] << 16);
    pl.w = (unsigned)ll[6] | ((unsigned)ll[7] << 16);
    const size_t o = ((size_t)b * SPAD + (y + 1) * 66 + 1 + sl) * 256 + cig * 32 + cg * 8;
    *reinterpret_cast<uint4*>(&xThi[o]) = ph;
    *reinterpret_cast<uint4*>(&xTlo[o]) = pl;
  }
}

// Weights: wb[co][q][ci] hi/lo from w[co][ci][3][3].
__global__ __launch_bounds__(256) void wbconv_kernel(
    const float* __restrict__ w_pam, const float* __restrict__ w_cam,
    unsigned short* __restrict__ wbhi, unsigned short* __restrict__ wblo)
{
  const int co = blockIdx.x;
  const float* wsrc = (co < CD) ? (w_pam + (size_t)co * KW9)
                                : (w_cam + (size_t)(co - CD) * KW9);
  const int t = threadIdx.x;
  #pragma unroll
  for (int i = 0; i < 9; ++i) {
    const int idx = i * 256 + t;
    const int q = idx >> 8, ci = idx & 255;
    unsigned short h, l;
    f2bf_pair(wsrc[ci * 9 + q], h, l);
    wbhi[(size_t)co * KW9 + idx] = h;
    wblo[(size_t)co * KW9 + idx] = l;
  }
}

// Implicit-GEMM conv3x3 via split-bf16 MFMA (fp32-equivalent precision).
// Per-wave: M=32 co x N=32 px. grid (128 px-tiles, 8 co-tiles, 2 b) = 2048 waves.
__global__ __launch_bounds__(64) void conv_mfma_kernel(
    const unsigned short* __restrict__ xThi, const unsigned short* __restrict__ xTlo,
    const unsigned short* __restrict__ wbhi, const unsigned short* __restrict__ wblo,
    float* __restrict__ out)
{
  const int pxt = blockIdx.x;
  const int cot = blockIdx.y;
  const int b = blockIdx.z;
  const int lane = threadIdx.x;
  const int m = lane & 15, g = lane >> 4;
  const int p0 = pxt * 32;
  const int y = p0 >> 6, x0 = p0 & 63;
  const int sbase = (y + 1) * 66 + (x0 + 1);
  const int co0 = cot * 32;

  const size_t xb = (size_t)b * SPAD * 256;

  f32x4 acc[2][2];
  #pragma unroll
  for (int mt = 0; mt < 2; ++mt)
    #pragma unroll
    for (int jt = 0; jt < 2; ++jt)
      #pragma unroll
      for (int r = 0; r < 4; ++r) acc[mt][jt][r] = 0.f;

  for (int q = 0; q < 9; ++q) {
    const int dq = (q / 3 - 1) * 66 + (q % 3 - 1);
    const unsigned short* xh0 = xThi + xb + (size_t)(sbase + m + dq) * 256;
    const unsigned short* xl0 = xTlo + xb + (size_t)(sbase + m + dq) * 256;
    const unsigned short* wh = wbhi + (size_t)(co0 + m) * KW9 + q * 256;
    const unsigned short* wl = wblo + (size_t)(co0 + m) * KW9 + q * 256;
    #pragma unroll
    for (int kk = 0; kk < 8; ++kk) {
      const int ko = kk * 32 + g * 8;
      const bf16x8 bh0 = *reinterpret_cast<const bf16x8*>(&xh0[ko]);
      const bf16x8 bl0 = *reinterpret_cast<const bf16x8*>(&xl0[ko]);
      const bf16x8 bh1 = *reinterpret_cast<const bf16x8*>(&xh0[16 * 256 + ko]);
      const bf16x8 bl1 = *reinterpret_cast<const bf16x8*>(&xl0[16 * 256 + ko]);
      #pragma unroll
      for (int mt = 0; mt < 2; ++mt) {
        const bf16x8 ah = *reinterpret_cast<const bf16x8*>(&wh[(size_t)mt * 16 * KW9 + ko]);
        const bf16x8 al = *reinterpret_cast<const bf16x8*>(&wl[(size_t)mt * 16 * KW9 + ko]);
        acc[mt][0] = __builtin_amdgcn_mfma_f32_16x16x32_bf16(ah, bh0, acc[mt][0], 0, 0, 0);
        acc[mt][1] = __builtin_amdgcn_mfma_f32_16x16x32_bf16(ah, bh1, acc[mt][1], 0, 0, 0);
        acc[mt][0] = __builtin_amdgcn_mfma_f32_16x16x32_bf16(ah, bl0, acc[mt][0], 0, 0, 0);
        acc[mt][1] = __builtin_amdgcn_mfma_f32_16x16x32_bf16(ah, bl1, acc[mt][1], 0, 0, 0);
        acc[mt][0] = __builtin_amdgcn_mfma_f32_16x16x32_bf16(al, bh0, acc[mt][0], 0, 0, 0);
        acc[mt][1] = __builtin_amdgcn_mfma_f32_16x16x32_bf16(al, bh1, acc[mt][1], 0, 0, 0);
      }
    }
  }

  #pragma unroll
  for (int mt = 0; mt < 2; ++mt)
    #pragma unroll
    for (int r = 0; r < 4; ++r) {
      const int co = co0 + mt * 16 + g * 4 + r;
      float* op = out + ((size_t)b * CO2 + co) * NPIX + p0 + m;
      op[0] = acc[mt][0][r];
      op[16] = acc[mt][1][r];
    }
}

// ---------------------------------------------------------------------------
__global__ __launch_bounds__(256) void gn_stats_kernel(
    const float* __restrict__ conv, float* __restrict__ meanb, float* __restrict__ rstdb)
{
  const int g = blockIdx.x;
  const float* base = conv + (size_t)g * (4 * NPIX);
  float s = 0.f, ss = 0.f;
  const float4* b4 = reinterpret_cast<const float4*>(base);
  for (int i = threadIdx.x; i < 4096; i += 256) {
    float4 v = b4[i];
    s += v.x + v.y + v.z + v.w;
    ss += v.x * v.x + v.y * v.y + v.z * v.z + v.w * v.w;
  }
  #pragma unroll
  for (int off = 32; off > 0; off >>= 1) {
    s += __shfl_down(s, off);
    ss += __shfl_down(ss, off);
  }
  __shared__ float rs[4], rss[4];
  const int lane = threadIdx.x & 63, wv = threadIdx.x >> 6;
  if (lane == 0) { rs[wv] = s; rss[wv] = ss; }
  __syncthreads();
  if (threadIdx.x == 0) {
    const float S = rs[0] + rs[1] + rs[2] + rs[3];
    const float SS = rss[0] + rss[1] + rss[2] + rss[3];
    const float inv = 1.f / 16384.f;
    const float m = S * inv;
    const float var = SS * inv - m * m;
    meanb[g] = m;
    rstdb[g] = rsqrtf(var + EPSV);
  }
}

__global__ __launch_bounds__(256) void gn_apply_kernel(
    float* __restrict__ conv, const float* __restrict__ meanb, const float* __restrict__ rstdb,
    const float* __restrict__ sc_pam, const float* __restrict__ bi_pam,
    const float* __restrict__ sc_cam, const float* __restrict__ bi_cam)
{
  const int idx = blockIdx.x * 256 + threadIdx.x;
  const int call = (idx >> 12) & 255;
  const int g = idx >> 14;
  const int head = call >> 7;
  const int c = call & 127;
  const float sc = head ? sc_cam[c] : sc_pam[c];
  const float bi = head ? bi_cam[c] : bi_pam[c];
  const float v = conv[idx];
  const float r = (v - meanb[g]) * rstdb[g] * sc + bi;
  conv[idx] = fmaxf(r, 0.f);
}

// ---------------------------------------------------------------------------
// bf16 copies of the PAM half: Pb[c][px] and Pt[px][c].
__global__ __launch_bounds__(256) void to_bf16_kernel(
    const float* __restrict__ conv, unsigned short* __restrict__ Pb,
    unsigned short* __restrict__ Pt)
{
  const int px0 = blockIdx.x * 64;
  const int c0  = blockIdx.y * 32;
  const int b   = blockIdx.z;
  __shared__ unsigned short Tl[32][76];
  const int t = threadIdx.x;
  {
    const int cl = t >> 3, pg = t & 7;
    const float* src = conv + ((size_t)b * CO2 + c0 + cl) * NPIX + px0 + pg * 8;
    const float4 v0 = *reinterpret_cast<const float4*>(src);
    const float4 v1 = *reinterpret_cast<const float4*>(src + 4);
    unsigned short h0 = f2bf(v0.x), h1 = f2bf(v0.y), h2 = f2bf(v0.z), h3 = f2bf(v0.w);
    unsigned short h4 = f2bf(v1.x), h5 = f2bf(v1.y), h6 = f2bf(v1.z), h7 = f2bf(v1.w);
    uint4 packed;
    packed.x = (unsigned)h0 | ((unsigned)h1 << 16);
    packed.y = (unsigned)h2 | ((unsigned)h3 << 16);
    packed.z = (unsigned)h4 | ((unsigned)h5 << 16);
    packed.w = (unsigned)h6 | ((unsigned)h7 << 16);
    unsigned short* dst = Pb + ((size_t)b * CD + c0 + cl) * NPIX + px0 + pg * 8;
    *reinterpret_cast<uint4*>(dst) = packed;
    Tl[cl][pg * 8 + 0] = h0; Tl[cl][pg * 8 + 1] = h1;
    Tl[cl][pg * 8 + 2] = h2; Tl[cl][pg * 8 + 3] = h3;
    Tl[cl][pg * 8 + 4] = h4; Tl[cl][pg * 8 + 5] = h5;
    Tl[cl][pg * 8 + 6] = h6; Tl[cl][pg * 8 + 7] = h7;
  }
  __syncthreads();
  {
    const int pl = t >> 2, cg = t & 3;
    unsigned short h[8];
    #pragma unroll
    for (int i = 0; i < 8; ++i) h[i] = Tl[cg * 8 + i][pl];
    uint4 packed;
    packed.x = (unsigned)h[0] | ((unsigned)h[1] << 16);
    packed.y = (unsigned)h[2] | ((unsigned)h[3] << 16);
    packed.z = (unsigned)h[4] | ((unsigned)h[5] << 16);
    packed.w = (unsigned)h[6] | ((unsigned)h[7] << 16);
    unsigned short* dst = Pt + ((size_t)b * NPIX + px0 + pl) * CD + c0 + cg * 8;
    *reinterpret_cast<uint4*>(dst) = packed;
  }
}

// ---------------------------------------------------------------------------
// PAM flash attention via bf16 MFMA. 4 waves/block, split-K + LDS merge.
__global__ __launch_bounds__(256) void pam_mfma_kernel(
    const float* __restrict__ conv, const unsigned short* __restrict__ Pb,
    const unsigned short* __restrict__ Pt, float* __restrict__ spam)
{
  const int b = blockIdx.y;
  const int q0 = blockIdx.x * 16;
  const int tid = threadIdx.x;
  const int w = tid >> 6;
  const int lane = tid & 63;
  const int m = lane & 15, g = lane >> 4;

  __shared__ __align__(16) unsigned short Sl[4][16 * 88];
  __shared__ float Obuf[4][16][129];
  __shared__ float mlm[4][16], mll[4][16], ltot[16];

  const unsigned short* PtB = Pt + (size_t)b * NPIX * CD;
  const unsigned short* PbB = Pb + (size_t)b * CD * NPIX;

  bf16x8 qf[4];
  #pragma unroll
  for (int kk = 0; kk < 4; ++kk)
    qf[kk] = *reinterpret_cast<const bf16x8*>(&PtB[(q0 + m) * CD + kk * 32 + g * 8]);

  f32x4 oacc[8];
  #pragma unroll
  for (int ct = 0; ct < 8; ++ct)
    #pragma unroll
    for (int r = 0; r < 4; ++r) oacc[ct][r] = 0.f;

  float mrow[4] = {-1e30f, -1e30f, -1e30f, -1e30f};
  float lrow[4] = {0.f, 0.f, 0.f, 0.f};

  for (int t = w * 16; t < w * 16 + 16; ++t) {
    const int j0 = t * 64;
    f32x4 sacc[4];
    #pragma unroll
    for (int jt = 0; jt < 4; ++jt)
      #pragma unroll
      for (int r = 0; r < 4; ++r) sacc[jt][r] = 0.f;
    #pragma unroll
    for (int jt = 0; jt < 4; ++jt) {
      #pragma unroll
      for (int kk = 0; kk < 4; ++kk) {
        const bf16x8 kf = *reinterpret_cast<const bf16x8*>(
            &PtB[(j0 + jt * 16 + m) * CD + kk * 32 + g * 8]);
        sacc[jt] = __builtin_amdgcn_mfma_f32_16x16x32_bf16(qf[kk], kf, sacc[jt], 0, 0, 0);
      }
    }
    float fac[4];
    #pragma unroll
    for (int r = 0; r < 4; ++r) {
      float v = fmaxf(fmaxf(sacc[0][r], sacc[1][r]), fmaxf(sacc[2][r], sacc[3][r]));
      v = fmaxf(v, __shfl_xor(v, 1));
      v = fmaxf(v, __shfl_xor(v, 2));
      v = fmaxf(v, __shfl_xor(v, 4));
      v = fmaxf(v, __shfl_xor(v, 8));
      const float mn = fmaxf(mrow[r], v);
      fac[r] = __expf(fmaxf(mrow[r] - mn, -80.f));
      mrow[r] = mn;
    }
    #pragma unroll
    for (int r = 0; r < 4; ++r) {
      float ls = 0.f;
      #pragma unroll
      for (int jt = 0; jt < 4; ++jt) {
        const float e = __expf(sacc[jt][r] - mrow[r]);
        ls += e;
        Sl[w][(g * 4 + r) * 88 + jt * 16 + m] = f2bf(e);
      }
      ls += __shfl_xor(ls, 1);
      ls += __shfl_xor(ls, 2);
      ls += __shfl_xor(ls, 4);
      ls += __shfl_xor(ls, 8);
      lrow[r] = lrow[r] * fac[r] + ls;
    }
    const int sel = m & 3;
    float fsel = (sel == 0) ? fac[0] : (sel == 1) ? fac[1] : (sel == 2) ? fac[2] : fac[3];
    const float facq = __shfl(fsel, ((m >> 2) << 4) | sel);
    #pragma unroll
    for (int ct = 0; ct < 8; ++ct)
      #pragma unroll
      for (int r = 0; r < 4; ++r) oacc[ct][r] *= facq;
    bf16x8 pf[2];
    #pragma unroll
    for (int kt = 0; kt < 2; ++kt)
      pf[kt] = *reinterpret_cast<const bf16x8*>(&Sl[w][m * 88 + kt * 32 + g * 8]);
    #pragma unroll
    for (int ct = 0; ct < 8; ++ct) {
      #pragma unroll
      for (int kt = 0; kt < 2; ++kt) {
        const bf16x8 vf = *reinterpret_cast<const bf16x8*>(
            &PbB[(ct * 16 + m) * (size_t)NPIX + j0 + kt * 32 + g * 8]);
        oacc[ct] = __builtin_amdgcn_mfma_f32_16x16x32_bf16(vf, pf[kt], oacc[ct], 0, 0, 0);
      }
    }
  }

  const int sel = m & 3;
  float msel_ = (sel == 0) ? mrow[0] : (sel == 1) ? mrow[1] : (sel == 2) ? mrow[2] : mrow[3];
  const float mq = __shfl(msel_, ((m >> 2) << 4) | sel);
  float lsel_ = (sel == 0) ? lrow[0] : (sel == 1) ? lrow[1] : (sel == 2) ? lrow[2] : lrow[3];
  const float lq = __shfl(lsel_, ((m >> 2) << 4) | sel);
  if (g == 0) { mlm[w][m] = mq; mll[w][m] = lq; }
  __syncthreads();
  const float mstar = fmaxf(fmaxf(mlm[0][m], mlm[1][m]), fmaxf(mlm[2][m], mlm[3][m]));
  const float rsw = __expf(fmaxf(mq - mstar, -80.f));
  #pragma unroll
  for (int ct = 0; ct < 8; ++ct)
    #pragma unroll
    for (int r = 0; r < 4; ++r)
      Obuf[w][m][ct * 16 + g * 4 + r] = oacc[ct][r] * rsw;
  if (w == 0 && g == 0) {
    const float lt = mll[0][m] * __expf(fmaxf(mlm[0][m] - mstar, -80.f))
                   + mll[1][m] * __expf(fmaxf(mlm[1][m] - mstar, -80.f))
                   + mll[2][m] * __expf(fmaxf(mlm[2][m] - mstar, -80.f))
                   + mll[3][m] * __expf(fmaxf(mlm[3][m] - mstar, -80.f));
    ltot[m] = lt;
  }
  __syncthreads();
  const int c = tid >> 1;
  const int qh = (tid & 1) * 8;
  const float* cv = conv + ((size_t)b * CO2 + c) * NPIX + q0 + qh;
  float* op = spam + ((size_t)b * CD + c) * NPIX + q0 + qh;
  #pragma unroll
  for (int qq = 0; qq < 8; ++qq) {
    const int ql = qh + qq;
    const float o = Obuf[0][ql][c] + Obuf[1][ql][c] + Obuf[2][ql][c] + Obuf[3][ql][c];
    op[qq] = cv[qq] + o / ltot[ql];
  }
}

// ---------------------------------------------------------------------------
// CAM gram split-K: 32 slices of K=128; LDS-staged, 8x8 register tile.
__global__ __launch_bounds__(256) void cam_gram_kernel(
    const float* __restrict__ conv, float* __restrict__ gpart)
{
  const int slice = blockIdx.x;  // 0..31
  const int b = blockIdx.y;
  const float* Am = conv + ((size_t)b * CO2 + CD) * NPIX;
  __shared__ float As[128][65];
  const int tid = threadIdx.x;
  const int cgrp = tid >> 4, dgrp = tid & 15;
  float acc[8][8];
  #pragma unroll
  for (int i = 0; i < 8; ++i)
    #pragma unroll
    for (int j = 0; j < 8; ++j) acc[i][j] = 0.f;
  const int nn = tid & 63, c0 = tid >> 6;
  for (int sub = 0; sub < 2; ++sub) {
    const int n0 = slice * 128 + sub * 64;
    __syncthreads();
    #pragma unroll
    for (int k = 0; k < 32; ++k)
      As[c0 + 4 * k][nn] = Am[(size_t)(c0 + 4 * k) * NPIX + n0 + nn];
    __syncthreads();
    #pragma unroll 4
    for (int n = 0; n < 64; ++n) {
      float av[8], bv[8];
      #pragma unroll
      for (int i = 0; i < 8; ++i) av[i] = As[8 * cgrp + i][n];
      #pragma unroll
      for (int j = 0; j < 8; ++j) bv[j] = As[8 * dgrp + j][n];
      #pragma unroll
      for (int i = 0; i < 8; ++i)
        #pragma unroll
        for (int j = 0; j < 8; ++j)
          acc[i][j] += av[i] * bv[j];
    }
  }
  float* gp = gpart + (((size_t)slice * BB + b) * CD + 8 * cgrp) * CD + 8 * dgrp;
  #pragma unroll
  for (int i = 0; i < 8; ++i)
    #pragma unroll
    for (int j = 0; j < 8; ++j)
      gp[i * CD + j] = acc[i][j];
}

// Reduce 32 partials + row softmax -> camw[b][c][d]
__global__ __launch_bounds__(128) void cam_softmax_kernel(
    const float* __restrict__ gpart, float* __restrict__ camw)
{
  const int bc = blockIdx.x;
  const int b = bc >> 7, c = bc & 127;
  const int d = threadIdx.x;
  float g = 0.f;
  for (int s = 0; s < 32; ++s)
    g += gpart[(((size_t)s * BB + b) * CD + c) * CD + d];
  float m = g;
  #pragma unroll
  for (int off = 32; off > 0; off >>= 1) m = fmaxf(m, __shfl_xor(m, off));
  __shared__ float sm[2], ssum[2];
  const int lane = d & 63, wv = d >> 6;
  if (lane == 0) sm[wv] = m;
  __syncthreads();
  m = fmaxf(sm[0], sm[1]);
  const float e = __expf(g - m);
  float s = e;
  #pragma unroll
  for (int off = 32; off > 0; off >>= 1) s += __shfl_xor(s, off);
  if (lane == 0) ssum[wv] = s;
  __syncthreads();
  camw[(size_t)bc * CD + d] = e / (ssum[0] + ssum[1]);
}

// sum_cam = cam + camw @ Am. Block: (4 ntiles, 32 c-rows, b); thread: 4c x 4n.
__global__ __launch_bounds__(256) void cam_apply_kernel(
    const float* __restrict__ conv, const float* __restrict__ camw, float* __restrict__ scam)
{
  const int b = blockIdx.z;
  const int c0 = blockIdx.y * 4;
  const int n = blockIdx.x * 1024 + threadIdx.x;
  const float* Am = conv + ((size_t)b * CO2 + CD) * NPIX;
  const float* Wr = camw + ((size_t)b * CD + c0) * CD;
  float acc[4][4];
  #pragma unroll
  for (int i = 0; i < 4; ++i)
    #pragma unroll
    for (int k = 0; k < 4; ++k) acc[i][k] = 0.f;
  for (int d = 0; d < CD; ++d) {
    const float w0 = Wr[d], w1 = Wr[CD + d], w2 = Wr[2 * CD + d], w3 = Wr[3 * CD + d];
    #pragma unroll
    for (int k = 0; k < 4; ++k) {
      const float a = Am[(size_t)d * NPIX + n + k * 256];
      acc[0][k] += w0 * a; acc[1][k] += w1 * a;
      acc[2][k] += w2 * a; acc[3][k] += w3 * a;
    }
  }
  #pragma unroll
  for (int i = 0; i < 4; ++i)
    #pragma unroll
    for (int k = 0; k < 4; ++k)
      scam[((size_t)b * CD + c0 + i) * NPIX + n + k * 256] =
          Am[(size_t)(c0 + i) * NPIX + n + k * 256] + acc[i][k];
}

// ---------------------------------------------------------------------------
__global__ __launch_bounds__(256) void pred_kernel(
    const float* __restrict__ spam, const float* __restrict__ scam,
    const float* __restrict__ wpred, const float* __restrict__ bpred,
    float* __restrict__ logit)
{
  const int b = blockIdx.y;
  const int p = blockIdx.x * 256 + threadIdx.x;
  float acc[KOUT];
  #pragma unroll
  for (int k = 0; k < KOUT; ++k) acc[k] = bpred[k];
  const float* sp = spam + (size_t)b * CD * NPIX + p;
  const float* sc = scam + (size_t)b * CD * NPIX + p;
  for (int c = 0; c < CD; ++c) {
    const float f = sp[(size_t)c * NPIX] + sc[(size_t)c * NPIX];
    #pragma unroll
    for (int k = 0; k < KOUT; ++k)
      acc[k] += f * wpred[k * CD + c];
  }
  #pragma unroll
  for (int k = 0; k < KOUT; ++k)
    logit[((size_t)b * KOUT + k) * NPIX + p] = acc[k];
}

__global__ __launch_bounds__(256) void upsample_kernel(
    const float* __restrict__ logit, float* __restrict__ out)
{
  const int idx = blockIdx.x * 256 + threadIdx.x;
  if (idx >= BB * KOUT * 256 * 256) return;
  const int ox = idx & 255;
  const int oy = (idx >> 8) & 255;
  const int plane = idx >> 16;
  const float* src = logit + (size_t)plane * NPIX;
  const float sy = (oy + 0.5f) * 0.25f - 0.5f;
  const float sx = (ox + 0.5f) * 0.25f - 0.5f;
  const float fyf = floorf(sy), fxf = floorf(sx);
  const float wy = sy - fyf, wx = sx - fxf;
  const int y0 = (int)fyf, x0 = (int)fxf;
  const int y0c = y0 < 0 ? 0 : y0;
  const int y1c = (y0 + 1 > 63) ? 63 : y0 + 1;
  const int x0c = x0 < 0 ? 0 : x0;
  const int x1c = (x0 + 1 > 63) ? 63 : x0 + 1;
  const float v00 = src[y0c * 64 + x0c], v01 = src[y0c * 64 + x1c];
  const float v10 = src[y1c * 64 + x0c], v11 = src[y1c * 64 + x1c];
  const float top = v00 + (v01 - v00) * wx;
  const float bot = v10 + (v11 - v10) * wx;
  out[idx] = top + (bot - top) * wy;
}

// ---------------------------------------------------------------------------
extern "C" void kernel_launch(void* const* d_in, const int* in_sizes, int n_in,
                              void* d_out, int out_size, void* d_ws, size_t ws_size,
                              hipStream_t stream) {
  (void)in_sizes; (void)n_in; (void)out_size; (void)ws_size;
  const float* x      = (const float*)d_in[0];
  const float* w_pam  = (const float*)d_in[1];
  const float* s_pam  = (const float*)d_in[2];
  const float* b_pam  = (const float*)d_in[3];
  const float* w_cam  = (const float*)d_in[4];
  const float* s_cam  = (const float*)d_in[5];
  const float* b_cam  = (const float*)d_in[6];
  const float* w_pred = (const float*)d_in[7];
  const float* b_pred = (const float*)d_in[8];
  float* out_f = (float*)d_out;
  float* ws0 = (float*)d_ws;

  // workspace layout (floats), total 5,138,688 = 20.55 MB
  // conv   [0,          2,097,152)
  // xT/wb  [2,097,152,  4,917,248)  -- dead after conv_mfma; then:
  //   Pb    [2,097,152, 2,621,440)
  //   Pt    [2,621,440, 3,145,728)
  //   gpart [3,145,728, 4,194,304)  = 32*2*128*128 floats
  // camw   [4,950,016,  4,982,784)
  // meanb  [4,982,784,  4,982,912)
  // rstdb  [4,982,912,  4,983,040)
  // logit  [4,983,040,  5,138,688)
  float* conv  = ws0;
  unsigned short* xThi = (unsigned short*)(ws0 + 2097152);
  unsigned short* xTlo = xThi + (size_t)BB * SPAD * 256;
  unsigned short* wbhi = (unsigned short*)(ws0 + 4327424);
  unsigned short* wblo = wbhi + (size_t)CO2 * KW9;
  float* gpart = ws0 + 3145728;
  float* camw  = ws0 + 4950016;
  float* meanb = ws0 + 4982784;
  float* rstdb = ws0 + 4982912;
  float* logit = ws0 + 4983040;

  unsigned short* Pb = xThi;
  unsigned short* Pt = Pb + 1048576;

  float* spam = out_f;
  float* scam = out_f + 1048576;

  zfill_kernel<<<2178, 256, 0, stream>>>((uint4*)xThi);
  xpose_kernel<<<dim3(64, 8, 2), 256, 0, stream>>>(x, xThi, xTlo);
  wbconv_kernel<<<256, 256, 0, stream>>>(w_pam, w_cam, wbhi, wblo);
  conv_mfma_kernel<<<dim3(128, 8, 2), 64, 0, stream>>>(xThi, xTlo, wbhi, wblo, conv);
  gn_stats_kernel<<<128, 256, 0, stream>>>(conv, meanb, rstdb);
  gn_apply_kernel<<<8192, 256, 0, stream>>>(conv, meanb, rstdb, s_pam, b_pam, s_cam, b_cam);
  to_bf16_kernel<<<dim3(64, 4, 2), 256, 0, stream>>>(conv, Pb, Pt);
  cam_gram_kernel<<<dim3(32, 2), 256, 0, stream>>>(conv, gpart);
  cam_softmax_kernel<<<256, 128, 0, stream>>>(gpart, camw);
  cam_apply_kernel<<<dim3(4, 32, 2), 256, 0, stream>>>(conv, camw, scam);
  pam_mfma_kernel<<<dim3(256, 2), 256, 0, stream>>>(conv, Pb, Pt, spam);
  pred_kernel<<<dim3(16, 2), 256, 0, stream>>>(spam, scam, w_pred, b_pred, logit);
  upsample_kernel<<<9728, 256, 0, stream>>>(logit, out_f);
}

// Round 11
// 369.832 us; speedup vs baseline: 6.6459x; 1.0533x over previous
//
#include <hip/hip_runtime.h>

#define BB 2
#define CIN 256
#define HH 64
#define WW 64
#define NPIX 4096
#define CD 128
#define CO2 256
#define KOUT 19
#define EPSV 1e-5f
#define SPAD 4356   // 66*66 padded spatial
#define KW9 2304    // 256*9

typedef __attribute__((ext_vector_type(8))) short bf16x8;
typedef __attribute__((ext_vector_type(4))) float f32x4;

__device__ inline unsigned short f2bf(float f) {
  unsigned u = __float_as_uint(f);
  u += 0x7fffu + ((u >> 16) & 1u);   // RNE
  return (unsigned short)(u >> 16);
}
__device__ inline float bf2f(unsigned short h) {
  return __uint_as_float((unsigned)h << 16);
}
__device__ inline void f2bf_pair(float f, unsigned short& hi, unsigned short& lo) {
  hi = f2bf(f);
  const float fhi = __uint_as_float((unsigned)hi << 16);
  lo = f2bf(f - fhi);
}

// ---------------------------------------------------------------------------
// zero-fill xT_hi and xT_lo (2 * 2,230,272 bf16 = 557,568 uint4)
__global__ __launch_bounds__(256) void zfill_kernel(uint4* __restrict__ p)
{
  const int i = blockIdx.x * 256 + threadIdx.x;
  if (i < 557568) p[i] = make_uint4(0, 0, 0, 0);
}

// Transpose+pad: xT[b][(y+1)*66+(x+1)][ci] (hi/lo bf16) from x[b][ci][y*64+x].
__global__ __launch_bounds__(256) void xpose_kernel(
    const float* __restrict__ x, unsigned short* __restrict__ xThi,
    unsigned short* __restrict__ xTlo)
{
  const int y = blockIdx.x;
  const int cig = blockIdx.y;
  const int b = blockIdx.z;
  __shared__ float Tl[32][65];
  const int t = threadIdx.x;
  {
    const int cl = t >> 3, pg = t & 7;
    const float* src = x + ((size_t)(b * CIN + cig * 32 + cl)) * NPIX + y * 64 + pg * 8;
    const float4 v0 = *reinterpret_cast<const float4*>(src);
    const float4 v1 = *reinterpret_cast<const float4*>(src + 4);
    Tl[cl][pg * 8 + 0] = v0.x; Tl[cl][pg * 8 + 1] = v0.y;
    Tl[cl][pg * 8 + 2] = v0.z; Tl[cl][pg * 8 + 3] = v0.w;
    Tl[cl][pg * 8 + 4] = v1.x; Tl[cl][pg * 8 + 5] = v1.y;
    Tl[cl][pg * 8 + 6] = v1.z; Tl[cl][pg * 8 + 7] = v1.w;
  }
  __syncthreads();
  {
    const int sl = t >> 2, cg = t & 3;
    unsigned short hh[8], ll[8];
    #pragma unroll
    for (int i = 0; i < 8; ++i) f2bf_pair(Tl[cg * 8 + i][sl], hh[i], ll[i]);
    uint4 ph, pl;
    ph.x = (unsigned)hh[0] | ((unsigned)hh[1] << 16);
    ph.y = (unsigned)hh[2] | ((unsigned)hh[3] << 16);
    ph.z = (unsigned)hh[4] | ((unsigned)hh[5] << 16);
    ph.w = (unsigned)hh[6] | ((unsigned)hh[7] << 16);
    pl.x = (unsigned)ll[0] | ((unsigned)ll[1] << 16);
    pl.y = (unsigned)ll[2] | ((unsigned)ll[3] << 16);
    pl.z = (unsigned)ll[4] | ((unsigned)ll[5] << 16);
    pl.w = (unsigned)ll[6] | ((unsigned)ll[7] << 16);
    const size_t o = ((size_t)b * SPAD + (y + 1) * 66 + 1 + sl) * 256 + cig * 32 + cg * 8;
    *reinterpret_cast<uint4*>(&xThi[o]) = ph;
    *reinterpret_cast<uint4*>(&xTlo[o]) = pl;
  }
}

// Weights: wb[co][q][ci] hi/lo from w[co][ci][3][3].
__global__ __launch_bounds__(256) void wbconv_kernel(
    const float* __restrict__ w_pam, const float* __restrict__ w_cam,
    unsigned short* __restrict__ wbhi, unsigned short* __restrict__ wblo)
{
  const int co = blockIdx.x;
  const float* wsrc = (co < CD) ? (w_pam + (size_t)co * KW9)
                                : (w_cam + (size_t)(co - CD) * KW9);
  const int t = threadIdx.x;
  #pragma unroll
  for (int i = 0; i < 9; ++i) {
    const int idx = i * 256 + t;
    const int q = idx >> 8, ci = idx & 255;
    unsigned short h, l;
    f2bf_pair(wsrc[ci * 9 + q], h, l);
    wbhi[(size_t)co * KW9 + idx] = h;
    wblo[(size_t)co * KW9 + idx] = l;
  }
}

// Implicit-GEMM conv3x3 via split-bf16 MFMA (fp32-equivalent precision).
// Per-wave: M=32 co x N=32 px. grid (128 px-tiles, 8 co-tiles, 2 b) = 2048 waves.
__global__ __launch_bounds__(64) void conv_mfma_kernel(
    const unsigned short* __restrict__ xThi, const unsigned short* __restrict__ xTlo,
    const unsigned short* __restrict__ wbhi, const unsigned short* __restrict__ wblo,
    float* __restrict__ out)
{
  const int pxt = blockIdx.x;
  const int cot = blockIdx.y;
  const int b = blockIdx.z;
  const int lane = threadIdx.x;
  const int m = lane & 15, g = lane >> 4;
  const int p0 = pxt * 32;
  const int y = p0 >> 6, x0 = p0 & 63;
  const int sbase = (y + 1) * 66 + (x0 + 1);
  const int co0 = cot * 32;

  const size_t xb = (size_t)b * SPAD * 256;

  f32x4 acc[2][2];
  #pragma unroll
  for (int mt = 0; mt < 2; ++mt)
    #pragma unroll
    for (int jt = 0; jt < 2; ++jt)
      #pragma unroll
      for (int r = 0; r < 4; ++r) acc[mt][jt][r] = 0.f;

  for (int q = 0; q < 9; ++q) {
    const int dq = (q / 3 - 1) * 66 + (q % 3 - 1);
    const unsigned short* xh0 = xThi + xb + (size_t)(sbase + m + dq) * 256;
    const unsigned short* xl0 = xTlo + xb + (size_t)(sbase + m + dq) * 256;
    const unsigned short* wh = wbhi + (size_t)(co0 + m) * KW9 + q * 256;
    const unsigned short* wl = wblo + (size_t)(co0 + m) * KW9 + q * 256;
    #pragma unroll
    for (int kk = 0; kk < 8; ++kk) {
      const int ko = kk * 32 + g * 8;
      const bf16x8 bh0 = *reinterpret_cast<const bf16x8*>(&xh0[ko]);
      const bf16x8 bl0 = *reinterpret_cast<const bf16x8*>(&xl0[ko]);
      const bf16x8 bh1 = *reinterpret_cast<const bf16x8*>(&xh0[16 * 256 + ko]);
      const bf16x8 bl1 = *reinterpret_cast<const bf16x8*>(&xl0[16 * 256 + ko]);
      #pragma unroll
      for (int mt = 0; mt < 2; ++mt) {
        const bf16x8 ah = *reinterpret_cast<const bf16x8*>(&wh[(size_t)mt * 16 * KW9 + ko]);
        const bf16x8 al = *reinterpret_cast<const bf16x8*>(&wl[(size_t)mt * 16 * KW9 + ko]);
        acc[mt][0] = __builtin_amdgcn_mfma_f32_16x16x32_bf16(ah, bh0, acc[mt][0], 0, 0, 0);
        acc[mt][1] = __builtin_amdgcn_mfma_f32_16x16x32_bf16(ah, bh1, acc[mt][1], 0, 0, 0);
        acc[mt][0] = __builtin_amdgcn_mfma_f32_16x16x32_bf16(ah, bl0, acc[mt][0], 0, 0, 0);
        acc[mt][1] = __builtin_amdgcn_mfma_f32_16x16x32_bf16(ah, bl1, acc[mt][1], 0, 0, 0);
        acc[mt][0] = __builtin_amdgcn_mfma_f32_16x16x32_bf16(al, bh0, acc[mt][0], 0, 0, 0);
        acc[mt][1] = __builtin_amdgcn_mfma_f32_16x16x32_bf16(al, bh1, acc[mt][1], 0, 0, 0);
      }
    }
  }

  #pragma unroll
  for (int mt = 0; mt < 2; ++mt)
    #pragma unroll
    for (int r = 0; r < 4; ++r) {
      const int co = co0 + mt * 16 + g * 4 + r;
      float* op = out + ((size_t)b * CO2 + co) * NPIX + p0 + m;
      op[0] = acc[mt][0][r];
      op[16] = acc[mt][1][r];
    }
}

// ---------------------------------------------------------------------------
__global__ __launch_bounds__(256) void gn_stats_kernel(
    const float* __restrict__ conv, float* __restrict__ meanb, float* __restrict__ rstdb)
{
  const int g = blockIdx.x;
  const float* base = conv + (size_t)g * (4 * NPIX);
  float s = 0.f, ss = 0.f;
  const float4* b4 = reinterpret_cast<const float4*>(base);
  for (int i = threadIdx.x; i < 4096; i += 256) {
    float4 v = b4[i];
    s += v.x + v.y + v.z + v.w;
    ss += v.x * v.x + v.y * v.y + v.z * v.z + v.w * v.w;
  }
  #pragma unroll
  for (int off = 32; off > 0; off >>= 1) {
    s += __shfl_down(s, off);
    ss += __shfl_down(ss, off);
  }
  __shared__ float rs[4], rss[4];
  const int lane = threadIdx.x & 63, wv = threadIdx.x >> 6;
  if (lane == 0) { rs[wv] = s; rss[wv] = ss; }
  __syncthreads();
  if (threadIdx.x == 0) {
    const float S = rs[0] + rs[1] + rs[2] + rs[3];
    const float SS = rss[0] + rss[1] + rss[2] + rss[3];
    const float inv = 1.f / 16384.f;
    const float m = S * inv;
    const float var = SS * inv - m * m;
    meanb[g] = m;
    rstdb[g] = rsqrtf(var + EPSV);
  }
}

__global__ __launch_bounds__(256) void gn_apply_kernel(
    float* __restrict__ conv, const float* __restrict__ meanb, const float* __restrict__ rstdb,
    const float* __restrict__ sc_pam, const float* __restrict__ bi_pam,
    const float* __restrict__ sc_cam, const float* __restrict__ bi_cam)
{
  const int idx = blockIdx.x * 256 + threadIdx.x;
  const int call = (idx >> 12) & 255;
  const int g = idx >> 14;
  const int head = call >> 7;
  const int c = call & 127;
  const float sc = head ? sc_cam[c] : sc_pam[c];
  const float bi = head ? bi_cam[c] : bi_pam[c];
  const float v = conv[idx];
  const float r = (v - meanb[g]) * rstdb[g] * sc + bi;
  conv[idx] = fmaxf(r, 0.f);
}

// ---------------------------------------------------------------------------
// bf16 copies of the PAM half: Pb[c][px] and Pt[px][c].
__global__ __launch_bounds__(256) void to_bf16_kernel(
    const float* __restrict__ conv, unsigned short* __restrict__ Pb,
    unsigned short* __restrict__ Pt)
{
  const int px0 = blockIdx.x * 64;
  const int c0  = blockIdx.y * 32;
  const int b   = blockIdx.z;
  __shared__ unsigned short Tl[32][76];
  const int t = threadIdx.x;
  {
    const int cl = t >> 3, pg = t & 7;
    const float* src = conv + ((size_t)b * CO2 + c0 + cl) * NPIX + px0 + pg * 8;
    const float4 v0 = *reinterpret_cast<const float4*>(src);
    const float4 v1 = *reinterpret_cast<const float4*>(src + 4);
    unsigned short h0 = f2bf(v0.x), h1 = f2bf(v0.y), h2 = f2bf(v0.z), h3 = f2bf(v0.w);
    unsigned short h4 = f2bf(v1.x), h5 = f2bf(v1.y), h6 = f2bf(v1.z), h7 = f2bf(v1.w);
    uint4 packed;
    packed.x = (unsigned)h0 | ((unsigned)h1 << 16);
    packed.y = (unsigned)h2 | ((unsigned)h3 << 16);
    packed.z = (unsigned)h4 | ((unsigned)h5 << 16);
    packed.w = (unsigned)h6 | ((unsigned)h7 << 16);
    unsigned short* dst = Pb + ((size_t)b * CD + c0 + cl) * NPIX + px0 + pg * 8;
    *reinterpret_cast<uint4*>(dst) = packed;
    Tl[cl][pg * 8 + 0] = h0; Tl[cl][pg * 8 + 1] = h1;
    Tl[cl][pg * 8 + 2] = h2; Tl[cl][pg * 8 + 3] = h3;
    Tl[cl][pg * 8 + 4] = h4; Tl[cl][pg * 8 + 5] = h5;
    Tl[cl][pg * 8 + 6] = h6; Tl[cl][pg * 8 + 7] = h7;
  }
  __syncthreads();
  {
    const int pl = t >> 2, cg = t & 3;
    unsigned short h[8];
    #pragma unroll
    for (int i = 0; i < 8; ++i) h[i] = Tl[cg * 8 + i][pl];
    uint4 packed;
    packed.x = (unsigned)h[0] | ((unsigned)h[1] << 16);
    packed.y = (unsigned)h[2] | ((unsigned)h[3] << 16);
    packed.z = (unsigned)h[4] | ((unsigned)h[5] << 16);
    packed.w = (unsigned)h[6] | ((unsigned)h[7] << 16);
    unsigned short* dst = Pt + ((size_t)b * NPIX + px0 + pl) * CD + c0 + cg * 8;
    *reinterpret_cast<uint4*>(dst) = packed;
  }
}

// ---------------------------------------------------------------------------
// PAM flash attention via bf16 MFMA. 8 waves/block split-K (512 keys each);
// bf16 LDS merge of (m, l, O) partials. 512 blocks x 8 waves = 16 waves/CU.
__global__ __launch_bounds__(512) void pam_mfma_kernel(
    const float* __restrict__ conv, const unsigned short* __restrict__ Pb,
    const unsigned short* __restrict__ Pt, float* __restrict__ spam)
{
  const int b = blockIdx.y;
  const int q0 = blockIdx.x * 16;
  const int tid = threadIdx.x;
  const int w = tid >> 6;            // wave 0..7
  const int lane = tid & 63;
  const int m = lane & 15, g = lane >> 4;

  __shared__ __align__(16) unsigned short Sl[8][16 * 88];   // 22,528 B
  __shared__ unsigned short Obuf[8][16][130];               // 33,280 B (bf16 partials)
  __shared__ float mlm[8][16], mll[8][16], ltot[16];

  const unsigned short* PtB = Pt + (size_t)b * NPIX * CD;
  const unsigned short* PbB = Pb + (size_t)b * CD * NPIX;

  bf16x8 qf[4];
  #pragma unroll
  for (int kk = 0; kk < 4; ++kk)
    qf[kk] = *reinterpret_cast<const bf16x8*>(&PtB[(q0 + m) * CD + kk * 32 + g * 8]);

  f32x4 oacc[8];
  #pragma unroll
  for (int ct = 0; ct < 8; ++ct)
    #pragma unroll
    for (int r = 0; r < 4; ++r) oacc[ct][r] = 0.f;

  float mrow[4] = {-1e30f, -1e30f, -1e30f, -1e30f};
  float lrow[4] = {0.f, 0.f, 0.f, 0.f};

  for (int t = w * 8; t < w * 8 + 8; ++t) {
    const int j0 = t * 64;
    f32x4 sacc[4];
    #pragma unroll
    for (int jt = 0; jt < 4; ++jt)
      #pragma unroll
      for (int r = 0; r < 4; ++r) sacc[jt][r] = 0.f;
    #pragma unroll
    for (int jt = 0; jt < 4; ++jt) {
      #pragma unroll
      for (int kk = 0; kk < 4; ++kk) {
        const bf16x8 kf = *reinterpret_cast<const bf16x8*>(
            &PtB[(j0 + jt * 16 + m) * CD + kk * 32 + g * 8]);
        sacc[jt] = __builtin_amdgcn_mfma_f32_16x16x32_bf16(qf[kk], kf, sacc[jt], 0, 0, 0);
      }
    }
    float fac[4];
    #pragma unroll
    for (int r = 0; r < 4; ++r) {
      float v = fmaxf(fmaxf(sacc[0][r], sacc[1][r]), fmaxf(sacc[2][r], sacc[3][r]));
      v = fmaxf(v, __shfl_xor(v, 1));
      v = fmaxf(v, __shfl_xor(v, 2));
      v = fmaxf(v, __shfl_xor(v, 4));
      v = fmaxf(v, __shfl_xor(v, 8));
      const float mn = fmaxf(mrow[r], v);
      fac[r] = __expf(fmaxf(mrow[r] - mn, -80.f));
      mrow[r] = mn;
    }
    #pragma unroll
    for (int r = 0; r < 4; ++r) {
      float ls = 0.f;
      #pragma unroll
      for (int jt = 0; jt < 4; ++jt) {
        const float e = __expf(sacc[jt][r] - mrow[r]);
        ls += e;
        Sl[w][(g * 4 + r) * 88 + jt * 16 + m] = f2bf(e);
      }
      ls += __shfl_xor(ls, 1);
      ls += __shfl_xor(ls, 2);
      ls += __shfl_xor(ls, 4);
      ls += __shfl_xor(ls, 8);
      lrow[r] = lrow[r] * fac[r] + ls;
    }
    const int sel = m & 3;
    float fsel = (sel == 0) ? fac[0] : (sel == 1) ? fac[1] : (sel == 2) ? fac[2] : fac[3];
    const float facq = __shfl(fsel, ((m >> 2) << 4) | sel);
    #pragma unroll
    for (int ct = 0; ct < 8; ++ct)
      #pragma unroll
      for (int r = 0; r < 4; ++r) oacc[ct][r] *= facq;
    bf16x8 pf[2];
    #pragma unroll
    for (int kt = 0; kt < 2; ++kt)
      pf[kt] = *reinterpret_cast<const bf16x8*>(&Sl[w][m * 88 + kt * 32 + g * 8]);
    #pragma unroll
    for (int ct = 0; ct < 8; ++ct) {
      #pragma unroll
      for (int kt = 0; kt < 2; ++kt) {
        const bf16x8 vf = *reinterpret_cast<const bf16x8*>(
            &PbB[(ct * 16 + m) * (size_t)NPIX + j0 + kt * 32 + g * 8]);
        oacc[ct] = __builtin_amdgcn_mfma_f32_16x16x32_bf16(vf, pf[kt], oacc[ct], 0, 0, 0);
      }
    }
  }

  // ---- merge the 8 wave partials (bf16 O) ----
  const int sel = m & 3;
  float msel_ = (sel == 0) ? mrow[0] : (sel == 1) ? mrow[1] : (sel == 2) ? mrow[2] : mrow[3];
  const float mq = __shfl(msel_, ((m >> 2) << 4) | sel);
  float lsel_ = (sel == 0) ? lrow[0] : (sel == 1) ? lrow[1] : (sel == 2) ? lrow[2] : lrow[3];
  const float lq = __shfl(lsel_, ((m >> 2) << 4) | sel);
  if (g == 0) { mlm[w][m] = mq; mll[w][m] = lq; }
  __syncthreads();
  float mstar = mlm[0][m];
  #pragma unroll
  for (int s = 1; s < 8; ++s) mstar = fmaxf(mstar, mlm[s][m]);
  const float rsw = __expf(fmaxf(mq - mstar, -80.f));
  #pragma unroll
  for (int ct = 0; ct < 8; ++ct)
    #pragma unroll
    for (int r = 0; r < 4; ++r)
      Obuf[w][m][ct * 16 + g * 4 + r] = f2bf(oacc[ct][r] * rsw);
  if (w == 0 && g == 0) {
    float lt = 0.f;
    #pragma unroll
    for (int s = 0; s < 8; ++s)
      lt += mll[s][m] * __expf(fmaxf(mlm[s][m] - mstar, -80.f));
    ltot[m] = lt;
  }
  __syncthreads();
  // cooperative final write: 512 threads -> c = tid>>2, q quarter = (tid&3)*4
  const int c = tid >> 2;
  const int qh = (tid & 3) * 4;
  const float* cv = conv + ((size_t)b * CO2 + c) * NPIX + q0 + qh;
  float* op = spam + ((size_t)b * CD + c) * NPIX + q0 + qh;
  #pragma unroll
  for (int qq = 0; qq < 4; ++qq) {
    const int ql = qh + qq;
    float o = 0.f;
    #pragma unroll
    for (int s = 0; s < 8; ++s) o += bf2f(Obuf[s][ql][c]);
    op[qq] = cv[qq] + o / ltot[ql];
  }
}

// ---------------------------------------------------------------------------
// CAM gram split-K: 32 slices of K=128; LDS-staged, 8x8 register tile.
__global__ __launch_bounds__(256) void cam_gram_kernel(
    const float* __restrict__ conv, float* __restrict__ gpart)
{
  const int slice = blockIdx.x;  // 0..31
  const int b = blockIdx.y;
  const float* Am = conv + ((size_t)b * CO2 + CD) * NPIX;
  __shared__ float As[128][65];
  const int tid = threadIdx.x;
  const int cgrp = tid >> 4, dgrp = tid & 15;
  float acc[8][8];
  #pragma unroll
  for (int i = 0; i < 8; ++i)
    #pragma unroll
    for (int j = 0; j < 8; ++j) acc[i][j] = 0.f;
  const int nn = tid & 63, c0 = tid >> 6;
  for (int sub = 0; sub < 2; ++sub) {
    const int n0 = slice * 128 + sub * 64;
    __syncthreads();
    #pragma unroll
    for (int k = 0; k < 32; ++k)
      As[c0 + 4 * k][nn] = Am[(size_t)(c0 + 4 * k) * NPIX + n0 + nn];
    __syncthreads();
    #pragma unroll 4
    for (int n = 0; n < 64; ++n) {
      float av[8], bv[8];
      #pragma unroll
      for (int i = 0; i < 8; ++i) av[i] = As[8 * cgrp + i][n];
      #pragma unroll
      for (int j = 0; j < 8; ++j) bv[j] = As[8 * dgrp + j][n];
      #pragma unroll
      for (int i = 0; i < 8; ++i)
        #pragma unroll
        for (int j = 0; j < 8; ++j)
          acc[i][j] += av[i] * bv[j];
    }
  }
  float* gp = gpart + (((size_t)slice * BB + b) * CD + 8 * cgrp) * CD + 8 * dgrp;
  #pragma unroll
  for (int i = 0; i < 8; ++i)
    #pragma unroll
    for (int j = 0; j < 8; ++j)
      gp[i * CD + j] = acc[i][j];
}

// Reduce 32 partials + row softmax -> camw[b][c][d]
__global__ __launch_bounds__(128) void cam_softmax_kernel(
    const float* __restrict__ gpart, float* __restrict__ camw)
{
  const int bc = blockIdx.x;
  const int b = bc >> 7, c = bc & 127;
  const int d = threadIdx.x;
  float g = 0.f;
  for (int s = 0; s < 32; ++s)
    g += gpart[(((size_t)s * BB + b) * CD + c) * CD + d];
  float m = g;
  #pragma unroll
  for (int off = 32; off > 0; off >>= 1) m = fmaxf(m, __shfl_xor(m, off));
  __shared__ float sm[2], ssum[2];
  const int lane = d & 63, wv = d >> 6;
  if (lane == 0) sm[wv] = m;
  __syncthreads();
  m = fmaxf(sm[0], sm[1]);
  const float e = __expf(g - m);
  float s = e;
  #pragma unroll
  for (int off = 32; off > 0; off >>= 1) s += __shfl_xor(s, off);
  if (lane == 0) ssum[wv] = s;
  __syncthreads();
  camw[(size_t)bc * CD + d] = e / (ssum[0] + ssum[1]);
}

// sum_cam = cam + camw @ Am. Block: (4 ntiles, 32 c-rows, b); thread: 4c x 4n.
__global__ __launch_bounds__(256) void cam_apply_kernel(
    const float* __restrict__ conv, const float* __restrict__ camw, float* __restrict__ scam)
{
  const int b = blockIdx.z;
  const int c0 = blockIdx.y * 4;
  const int n = blockIdx.x * 1024 + threadIdx.x;
  const float* Am = conv + ((size_t)b * CO2 + CD) * NPIX;
  const float* Wr = camw + ((size_t)b * CD + c0) * CD;
  float acc[4][4];
  #pragma unroll
  for (int i = 0; i < 4; ++i)
    #pragma unroll
    for (int k = 0; k < 4; ++k) acc[i][k] = 0.f;
  for (int d = 0; d < CD; ++d) {
    const float w0 = Wr[d], w1 = Wr[CD + d], w2 = Wr[2 * CD + d], w3 = Wr[3 * CD + d];
    #pragma unroll
    for (int k = 0; k < 4; ++k) {
      const float a = Am[(size_t)d * NPIX + n + k * 256];
      acc[0][k] += w0 * a; acc[1][k] += w1 * a;
      acc[2][k] += w2 * a; acc[3][k] += w3 * a;
    }
  }
  #pragma unroll
  for (int i = 0; i < 4; ++i)
    #pragma unroll
    for (int k = 0; k < 4; ++k)
      scam[((size_t)b * CD + c0 + i) * NPIX + n + k * 256] =
          Am[(size_t)(c0 + i) * NPIX + n + k * 256] + acc[i][k];
}

// ---------------------------------------------------------------------------
__global__ __launch_bounds__(256) void pred_kernel(
    const float* __restrict__ spam, const float* __restrict__ scam,
    const float* __restrict__ wpred, const float* __restrict__ bpred,
    float* __restrict__ logit)
{
  const int b = blockIdx.y;
  const int p = blockIdx.x * 256 + threadIdx.x;
  float acc[KOUT];
  #pragma unroll
  for (int k = 0; k < KOUT; ++k) acc[k] = bpred[k];
  const float* sp = spam + (size_t)b * CD * NPIX + p;
  const float* sc = scam + (size_t)b * CD * NPIX + p;
  for (int c = 0; c < CD; ++c) {
    const float f = sp[(size_t)c * NPIX] + sc[(size_t)c * NPIX];
    #pragma unroll
    for (int k = 0; k < KOUT; ++k)
      acc[k] += f * wpred[k * CD + c];
  }
  #pragma unroll
  for (int k = 0; k < KOUT; ++k)
    logit[((size_t)b * KOUT + k) * NPIX + p] = acc[k];
}

__global__ __launch_bounds__(256) void upsample_kernel(
    const float* __restrict__ logit, float* __restrict__ out)
{
  const int idx = blockIdx.x * 256 + threadIdx.x;
  if (idx >= BB * KOUT * 256 * 256) return;
  const int ox = idx & 255;
  const int oy = (idx >> 8) & 255;
  const int plane = idx >> 16;
  const float* src = logit + (size_t)plane * NPIX;
  const float sy = (oy + 0.5f) * 0.25f - 0.5f;
  const float sx = (ox + 0.5f) * 0.25f - 0.5f;
  const float fyf = floorf(sy), fxf = floorf(sx);
  const float wy = sy - fyf, wx = sx - fxf;
  const int y0 = (int)fyf, x0 = (int)fxf;
  const int y0c = y0 < 0 ? 0 : y0;
  const int y1c = (y0 + 1 > 63) ? 63 : y0 + 1;
  const int x0c = x0 < 0 ? 0 : x0;
  const int x1c = (x0 + 1 > 63) ? 63 : x0 + 1;
  const float v00 = src[y0c * 64 + x0c], v01 = src[y0c * 64 + x1c];
  const float v10 = src[y1c * 64 + x0c], v11 = src[y1c * 64 + x1c];
  const float top = v00 + (v01 - v00) * wx;
  const float bot = v10 + (v11 - v10) * wx;
  out[idx] = top + (bot - top) * wy;
}

// ---------------------------------------------------------------------------
extern "C" void kernel_launch(void* const* d_in, const int* in_sizes, int n_in,
                              void* d_out, int out_size, void* d_ws, size_t ws_size,
                              hipStream_t stream) {
  (void)in_sizes; (void)n_in; (void)out_size; (void)ws_size;
  const float* x      = (const float*)d_in[0];
  const float* w_pam  = (const float*)d_in[1];
  const float* s_pam  = (const float*)d_in[2];
  const float* b_pam  = (const float*)d_in[3];
  const float* w_cam  = (const float*)d_in[4];
  const float* s_cam  = (const float*)d_in[5];
  const float* b_cam  = (const float*)d_in[6];
  const float* w_pred = (const float*)d_in[7];
  const float* b_pred = (const float*)d_in[8];
  float* out_f = (float*)d_out;
  float* ws0 = (float*)d_ws;

  // workspace layout (floats), total 5,138,688 = 20.55 MB (unchanged)
  float* conv  = ws0;
  unsigned short* xThi = (unsigned short*)(ws0 + 2097152);
  unsigned short* xTlo = xThi + (size_t)BB * SPAD * 256;
  unsigned short* wbhi = (unsigned short*)(ws0 + 4327424);
  unsigned short* wblo = wbhi + (size_t)CO2 * KW9;
  float* gpart = ws0 + 3145728;
  float* camw  = ws0 + 4950016;
  float* meanb = ws0 + 4982784;
  float* rstdb = ws0 + 4982912;
  float* logit = ws0 + 4983040;

  unsigned short* Pb = xThi;
  unsigned short* Pt = Pb + 1048576;

  float* spam = out_f;
  float* scam = out_f + 1048576;

  zfill_kernel<<<2178, 256, 0, stream>>>((uint4*)xThi);
  xpose_kernel<<<dim3(64, 8, 2), 256, 0, stream>>>(x, xThi, xTlo);
  wbconv_kernel<<<256, 256, 0, stream>>>(w_pam, w_cam, wbhi, wblo);
  conv_mfma_kernel<<<dim3(128, 8, 2), 64, 0, stream>>>(xThi, xTlo, wbhi, wblo, conv);
  gn_stats_kernel<<<128, 256, 0, stream>>>(conv, meanb, rstdb);
  gn_apply_kernel<<<8192, 256, 0, stream>>>(conv, meanb, rstdb, s_pam, b_pam, s_cam, b_cam);
  to_bf16_kernel<<<dim3(64, 4, 2), 256, 0, stream>>>(conv, Pb, Pt);
  cam_gram_kernel<<<dim3(32, 2), 256, 0, stream>>>(conv, gpart);
  cam_softmax_kernel<<<256, 128, 0, stream>>>(gpart, camw);
  cam_apply_kernel<<<dim3(4, 32, 2), 256, 0, stream>>>(conv, camw, scam);
  pam_mfma_kernel<<<dim3(256, 2), 512, 0, stream>>>(conv, Pb, Pt, spam);
  pred_kernel<<<dim3(16, 2), 256, 0, stream>>>(spam, scam, w_pred, b_pred, logit);
  upsample_kernel<<<9728, 256, 0, stream>>>(logit, out_f);
}